// Round 3
// baseline (10349.301 us; speedup 1.0000x reference)
//
#include <hip/hip_runtime.h>
#include <hip/hip_bf16.h>
#include <math.h>

#define HID 512
#define GATES 2048
#define BT 8192   // 32*256
#define TT 256
#define BB 32
#define DIN 768
#define NTAG 25
#define UPB 4     // hidden units per persistent block (per direction)
#define NBLK 128  // persistent blocks (each handles BOTH directions)
#define FSTR 4    // flag stride in ints (16 B)

__device__ __forceinline__ float sigf(float x) { return 1.f / (1.f + __expf(-x)); }

// ---------------- GEMM: xz = emb @ K(dir) + bias(dir) ----------------
__global__ __launch_bounds__(256) void gemm_xz(
    const float* __restrict__ A,
    const float* __restrict__ Kf, const float* __restrict__ Kb,
    const float* __restrict__ bf, const float* __restrict__ bb,
    float* __restrict__ xzf, float* __restrict__ xzb)
{
  const int bx = blockIdx.x;   // 0..31
  const int by = blockIdx.y;   // 0..63
  const int dir = bx >> 4;
  const float* __restrict__ B = dir ? Kb : Kf;
  const float* __restrict__ bias = dir ? bb : bf;
  float* __restrict__ C = dir ? xzb : xzf;
  const int col0 = (bx & 15) * 128;
  const int row0 = by * 128;

  __shared__ float As[8][128];
  __shared__ float Bs[8][128];

  const int tid = threadIdx.x;
  const int tx = tid & 15, ty = tid >> 4;
  float acc[8][8];
  #pragma unroll
  for (int i = 0; i < 8; ++i)
    #pragma unroll
    for (int j = 0; j < 8; ++j) acc[i][j] = 0.f;

  const int arow = tid >> 1, ak4 = (tid & 1) * 4;
  const int brow = tid >> 5, bcol4 = (tid & 31) * 4;

  for (int k0 = 0; k0 < DIN; k0 += 8) {
    const float4 av = *(const float4*)(A + (size_t)(row0 + arow) * DIN + k0 + ak4);
    const float4 bv = *(const float4*)(B + (size_t)(k0 + brow) * GATES + col0 + bcol4);
    __syncthreads();
    As[ak4 + 0][arow] = av.x;
    As[ak4 + 1][arow] = av.y;
    As[ak4 + 2][arow] = av.z;
    As[ak4 + 3][arow] = av.w;
    *(float4*)&Bs[brow][bcol4] = bv;
    __syncthreads();
    #pragma unroll
    for (int kk = 0; kk < 8; ++kk) {
      float a[8], bv2[8];
      #pragma unroll
      for (int i = 0; i < 8; ++i) a[i] = As[kk][ty * 8 + i];
      #pragma unroll
      for (int j = 0; j < 8; ++j) bv2[j] = Bs[kk][tx * 8 + j];
      #pragma unroll
      for (int i = 0; i < 8; ++i)
        #pragma unroll
        for (int j = 0; j < 8; ++j) acc[i][j] = fmaf(a[i], bv2[j], acc[i][j]);
    }
  }
  #pragma unroll
  for (int i = 0; i < 8; ++i) {
    const size_t row = row0 + ty * 8 + i;
    float* outp = C + row * GATES + col0 + tx * 8;
    #pragma unroll
    for (int j = 0; j < 8; ++j) outp[j] = acc[i][j] + bias[col0 + tx * 8 + j];
  }
}

// ---------------- Persistent dual-direction BiLSTM ----------------
// 128 blocks x 256 threads. Block blk owns hidden units [blk*4, blk*4+4) x 4
// gates = 16 columns for all 32 batches, for BOTH directions (R slices of both
// in registers). Per step: phase F then phase B; each phase waits on 128
// per-block flags (16B-strided plain stores, no RMW), stages h(s-1) to
// swizzled LDS, 32-batch reg accumulation, shfl+LDS reduce, gate math, h
// broadcast (agent-scope stores) + release flag. The other phase's compute
// hides each phase's flag-propagation latency.
__global__ __launch_bounds__(256, 1) void lstm_persist(
    const float* __restrict__ xzf, const float* __restrict__ xzb,
    const float* __restrict__ Rf, const float* __restrict__ Rb,
    float* __restrict__ hf, float* __restrict__ hb,
    float* __restrict__ hG,   // [2 dir][2 parity][32][512]
    int* __restrict__ flg)    // [2 dir][256 step][128 blk * FSTR]
{
  const int blk = blockIdx.x;          // 0..127
  const int u0 = blk * UPB;
  const int tid = threadIdx.x;
  const int c = tid & 15;
  const int r = tid >> 4;
  const int gt = c & 3, uu = c >> 2;
  const int j = gt * HID + u0 + uu;    // gate-major column

  __shared__ float hs[BB * HID];       // 64 KB, 16B-chunk XOR-swizzled
  __shared__ float red[BB][4][17];
  __shared__ float zbuf[BB][20];

  float RF[32], RB[32];
  {
    const int sw = r & 3;
    #pragma unroll
    for (int q = 0; q < 8; ++q) {
      const int kb = r * 32 + (q ^ sw) * 4;
      #pragma unroll
      for (int x = 0; x < 4; ++x) {
        RF[q * 4 + x] = Rf[(size_t)(kb + x) * GATES + j];
        RB[q * 4 + x] = Rb[(size_t)(kb + x) * GATES + j];
      }
    }
  }

  float cstF = 0.f, cstB = 0.f;
  const int b_o = tid & 31, u_o = tid >> 5;
  float4* hs4 = (float4*)hs;
  const int fb0 = r, fb1 = r + 16;

  float* __restrict__ hGF = hG;
  float* __restrict__ hGB = hG + 2 * BB * HID;
  int* __restrict__ flgF = flg;
  int* __restrict__ flgB = flg + TT * NBLK * FSTR;

#define PHASE(RR, xzp, tt, cst, houtp, hGp, flgp)                              \
  {                                                                            \
    const float x0 = xzp[((size_t)fb0 * TT + (tt)) * GATES + j];               \
    const float x1 = xzp[((size_t)fb1 * TT + (tt)) * GATES + j];               \
    if (s > 0) {                                                               \
      if (tid < NBLK) {                                                        \
        while (!__hip_atomic_load(&flgp[((s - 1) * NBLK + tid) * FSTR],        \
                                  __ATOMIC_RELAXED, __HIP_MEMORY_SCOPE_AGENT)) \
          __builtin_amdgcn_s_sleep(2);                                         \
      }                                                                        \
      __syncthreads();                                                         \
      __threadfence();                                                         \
    }                                                                          \
    {                                                                          \
      const float4* hsrc = (const float4*)(hGp + (size_t)pp * BB * HID);       \
      _Pragma("unroll")                                                        \
      for (int q2 = 0; q2 < 16; ++q2) {                                        \
        const int gidx = tid + q2 * 256;                                       \
        const float4 v = hsrc[gidx];                                           \
        const int b = gidx >> 7, k4 = gidx & 127;                              \
        const int rr = k4 >> 3, kk4 = k4 & 7;                                  \
        hs4[b * 128 + rr * 8 + (kk4 ^ (rr & 3))] = v;                          \
      }                                                                        \
    }                                                                          \
    __syncthreads();                                                           \
    float z[32];                                                               \
    {                                                                          \
      const float4* hp0 = hs4 + r * 8;                                         \
      _Pragma("unroll")                                                        \
      for (int b = 0; b < 32; ++b) {                                           \
        const float4* hp = hp0 + b * 128;                                      \
        float acc2 = 0.f;                                                      \
        _Pragma("unroll")                                                      \
        for (int q = 0; q < 8; ++q) {                                          \
          const float4 hv = hp[q];                                             \
          acc2 = fmaf(hv.x, RR[q * 4 + 0], acc2);                              \
          acc2 = fmaf(hv.y, RR[q * 4 + 1], acc2);                              \
          acc2 = fmaf(hv.z, RR[q * 4 + 2], acc2);                              \
          acc2 = fmaf(hv.w, RR[q * 4 + 3], acc2);                              \
        }                                                                      \
        z[b] = acc2;                                                           \
      }                                                                        \
    }                                                                          \
    _Pragma("unroll")                                                          \
    for (int b = 0; b < 32; ++b) {                                             \
      z[b] += __shfl_xor(z[b], 16);                                            \
      z[b] += __shfl_xor(z[b], 32);                                            \
    }                                                                          \
    {                                                                          \
      const int w = tid >> 6;                                                  \
      if ((tid & 48) == 0) {                                                   \
        _Pragma("unroll")                                                      \
        for (int b = 0; b < 32; ++b) red[b][w][c] = z[b];                      \
      }                                                                        \
    }                                                                          \
    __syncthreads();                                                           \
    {                                                                          \
      const float za = red[fb0][0][c] + red[fb0][1][c] + red[fb0][2][c] +      \
                       red[fb0][3][c] + x0;                                    \
      const float zb2 = red[fb1][0][c] + red[fb1][1][c] + red[fb1][2][c] +     \
                        red[fb1][3][c] + x1;                                   \
      zbuf[fb0][c] = za;                                                       \
      zbuf[fb1][c] = zb2;                                                      \
    }                                                                          \
    __syncthreads();                                                           \
    if (tid < 128) {                                                           \
      const float zi = zbuf[b_o][u_o * 4 + 0];                                 \
      const float zf = zbuf[b_o][u_o * 4 + 1];                                 \
      const float zg = zbuf[b_o][u_o * 4 + 2];                                 \
      const float zo = zbuf[b_o][u_o * 4 + 3];                                 \
      cst = sigf(zf) * cst + sigf(zi) * tanhf(zg);                             \
      const float h = sigf(zo) * tanhf(cst);                                   \
      houtp[((size_t)b_o * TT + (tt)) * HID + u0 + u_o] = h;                   \
      __hip_atomic_store(&hGp[(size_t)cp * BB * HID + b_o * HID + u0 + u_o],   \
                         h, __ATOMIC_RELAXED, __HIP_MEMORY_SCOPE_AGENT);       \
    }                                                                          \
    __syncthreads();                                                           \
    if (tid == 0)                                                              \
      __hip_atomic_store(&flgp[(s * NBLK + blk) * FSTR], 1, __ATOMIC_RELEASE,  \
                         __HIP_MEMORY_SCOPE_AGENT);                            \
  }

  for (int s = 0; s < TT; ++s) {
    const int pp = (s + 1) & 1;   // parity holding h(s-1)
    const int cp = s & 1;         // parity receiving h(s)
    PHASE(RF, xzf, s, cstF, hf, hGF, flgF);
    PHASE(RB, xzb, TT - 1 - s, cstB, hb, hGB, flgB);
  }
#undef PHASE
}

// ---------------- dense + SELU ----------------
__global__ __launch_bounds__(256) void dense_selu(
    const float* __restrict__ hf, const float* __restrict__ hb,
    const float* __restrict__ W, const float* __restrict__ bias,
    float* __restrict__ out)
{
  const int bt = blockIdx.x;
  __shared__ float h[1024];
  __shared__ float part[256];
  const int tid = threadIdx.x;
  if (tid < 128) ((float4*)h)[tid] = ((const float4*)(hf + (size_t)bt * 512))[tid];
  else           ((float4*)h)[tid] = ((const float4*)(hb + (size_t)bt * 512))[tid - 128];
  __syncthreads();
  const int n = tid >> 3, s = tid & 7;
  float acc = 0.f;
  if (n < NTAG) {
    const int k0 = s * 128;
    #pragma unroll 4
    for (int k = k0; k < k0 + 128; ++k) acc = fmaf(h[k], W[(size_t)k * NTAG + n], acc);
  }
  part[tid] = acc;
  __syncthreads();
  if (tid < NTAG) {
    float v = 0.f;
    #pragma unroll
    for (int q = 0; q < 8; ++q) v += part[tid * 8 + q];
    v += bias[tid];
    const float scale = 1.0507009873554805f, alf = 1.6732632423543772f;
    v = v > 0.f ? scale * v : scale * alf * (__expf(v) - 1.f);
    out[(size_t)bt * NTAG + tid] = v;
  }
}

// ---------------- CRF NLL ----------------
__global__ __launch_bounds__(64) void crf_kernel(
    const float* __restrict__ logits,
    const int* __restrict__ tags, const int* __restrict__ lens,
    const float* __restrict__ trans, float* __restrict__ nll)
{
  const int b = blockIdx.x;
  const int tid = threadIdx.x;
  __shared__ float tr[NTAG * NTAG];
  __shared__ float al[NTAG];
  __shared__ float red[2];
  for (int i = tid; i < NTAG * NTAG; i += 64) tr[i] = trans[i];
  __syncthreads();

  int len = lens[b];
  len = len < 1 ? 1 : (len > TT ? TT : len);
  const size_t base = (size_t)b * TT;

  float us = 0.f, bs = 0.f;
  for (int t = tid; t < TT; t += 64) {
    if (t < len) us += logits[(base + t) * NTAG + tags[base + t]];
    if (t >= 1 && t < len) bs += tr[tags[base + t - 1] * NTAG + tags[base + t]];
  }
  #pragma unroll
  for (int off = 32; off > 0; off >>= 1) {
    us += __shfl_down(us, off);
    bs += __shfl_down(bs, off);
  }
  if (tid == 0) { red[0] = us; red[1] = bs; }

  if (tid < NTAG) al[tid] = logits[base * NTAG + tid];
  __syncthreads();

  for (int t = 1; t < len; ++t) {
    float nv = 0.f;
    if (tid < NTAG) {
      float m = -3.4e38f;
      #pragma unroll
      for (int i = 0; i < NTAG; ++i) m = fmaxf(m, al[i] + tr[i * NTAG + tid]);
      float ss = 0.f;
      #pragma unroll
      for (int i = 0; i < NTAG; ++i) ss += __expf(al[i] + tr[i * NTAG + tid] - m);
      nv = m + __logf(ss) + logits[(base + t) * NTAG + tid];
    }
    __syncthreads();
    if (tid < NTAG) al[tid] = nv;
    __syncthreads();
  }

  if (tid == 0) {
    float m = -3.4e38f;
    for (int i = 0; i < NTAG; ++i) m = fmaxf(m, al[i]);
    float ss = 0.f;
    for (int i = 0; i < NTAG; ++i) ss += __expf(al[i] - m);
    const float logz = m + __logf(ss);
    nll[b] = -(red[0] + red[1] - logz);
  }
}

__global__ __launch_bounds__(64) void finalize(const float* __restrict__ nll, float* __restrict__ out) {
  float v = (threadIdx.x < BB) ? nll[threadIdx.x] : 0.f;
  #pragma unroll
  for (int off = 32; off > 0; off >>= 1) v += __shfl_down(v, off);
  if (threadIdx.x == 0) out[0] = v * (1.f / BB);
}

extern "C" void kernel_launch(void* const* d_in, const int* in_sizes, int n_in,
                              void* d_out, int out_size, void* d_ws, size_t ws_size,
                              hipStream_t stream) {
  const float* emb  = (const float*)d_in[0];
  const int* tags   = (const int*)d_in[1];
  const int* lens   = (const int*)d_in[2];
  const float* kf   = (const float*)d_in[3];
  const float* rf   = (const float*)d_in[4];
  const float* bf   = (const float*)d_in[5];
  const float* kb   = (const float*)d_in[6];
  const float* rb   = (const float*)d_in[7];
  const float* bb   = (const float*)d_in[8];
  const float* dw   = (const float*)d_in[9];
  const float* db   = (const float*)d_in[10];
  const float* trans= (const float*)d_in[11];
  float* out = (float*)d_out;

  float* ws  = (float*)d_ws;
  float* xzf = ws;
  float* xzb = xzf + (size_t)BT * GATES;
  float* hf  = xzb + (size_t)BT * GATES;
  float* hb  = hf + (size_t)BT * HID;
  float* nll = hb + (size_t)BT * HID;
  float* hG  = nll + 64;                       // 2*2*32*512 = 65536 floats
  int*   flg = (int*)(hG + 2 * 2 * BB * HID);  // 2*256*128*4 ints = 1 MB

  // zero h-exchange buffers and flags (required every call; graph-safe)
  hipMemsetAsync(hG, 0,
                 (size_t)(2 * 2 * BB * HID) * 4 + (size_t)(2 * TT * NBLK * FSTR) * 4,
                 stream);

  gemm_xz<<<dim3(32, 64), 256, 0, stream>>>(emb, kf, kb, bf, bb, xzf, xzb);
  lstm_persist<<<NBLK, 256, 0, stream>>>(xzf, xzb, rf, rb, hf, hb, hG, flg);
  dense_selu<<<8192, 256, 0, stream>>>(hf, hb, dw, db, out + 1);
  crf_kernel<<<32, 64, 0, stream>>>(out + 1, tags, lens, trans, nll);
  finalize<<<1, 64, 0, stream>>>(nll, out);
}

// Round 4
// 8766.425 us; speedup vs baseline: 1.1806x; 1.1806x over previous
//
#include <hip/hip_runtime.h>
#include <hip/hip_bf16.h>
#include <math.h>

#define HID 512
#define GATES 2048
#define BT 8192   // 32*256
#define TT 256
#define BB 32
#define DIN 768
#define NTAG 25
#define UPB 4     // hidden units per persistent block
#define NBLK 128  // blocks per direction
#define FSTR 4    // flag stride in ints (16 B)
#define EREP 8    // epoch flag replicas
#define ESTR 16   // epoch replica stride in ints (64 B)

__device__ __forceinline__ float sigf(float x) { return 1.f / (1.f + __expf(-x)); }

// ---------------- GEMM: xz = emb @ K(dir) + bias(dir) ----------------
__global__ __launch_bounds__(256) void gemm_xz(
    const float* __restrict__ A,
    const float* __restrict__ Kf, const float* __restrict__ Kb,
    const float* __restrict__ bf, const float* __restrict__ bb,
    float* __restrict__ xzf, float* __restrict__ xzb)
{
  const int bx = blockIdx.x;   // 0..31
  const int by = blockIdx.y;   // 0..63
  const int dir = bx >> 4;
  const float* __restrict__ B = dir ? Kb : Kf;
  const float* __restrict__ bias = dir ? bb : bf;
  float* __restrict__ C = dir ? xzb : xzf;
  const int col0 = (bx & 15) * 128;
  const int row0 = by * 128;

  __shared__ float As[8][128];
  __shared__ float Bs[8][128];

  const int tid = threadIdx.x;
  const int tx = tid & 15, ty = tid >> 4;
  float acc[8][8];
  #pragma unroll
  for (int i = 0; i < 8; ++i)
    #pragma unroll
    for (int j = 0; j < 8; ++j) acc[i][j] = 0.f;

  const int arow = tid >> 1, ak4 = (tid & 1) * 4;
  const int brow = tid >> 5, bcol4 = (tid & 31) * 4;

  for (int k0 = 0; k0 < DIN; k0 += 8) {
    const float4 av = *(const float4*)(A + (size_t)(row0 + arow) * DIN + k0 + ak4);
    const float4 bv = *(const float4*)(B + (size_t)(k0 + brow) * GATES + col0 + bcol4);
    __syncthreads();
    As[ak4 + 0][arow] = av.x;
    As[ak4 + 1][arow] = av.y;
    As[ak4 + 2][arow] = av.z;
    As[ak4 + 3][arow] = av.w;
    *(float4*)&Bs[brow][bcol4] = bv;
    __syncthreads();
    #pragma unroll
    for (int kk = 0; kk < 8; ++kk) {
      float a[8], bv2[8];
      #pragma unroll
      for (int i = 0; i < 8; ++i) a[i] = As[kk][ty * 8 + i];
      #pragma unroll
      for (int j = 0; j < 8; ++j) bv2[j] = Bs[kk][tx * 8 + j];
      #pragma unroll
      for (int i = 0; i < 8; ++i)
        #pragma unroll
        for (int j = 0; j < 8; ++j) acc[i][j] = fmaf(a[i], bv2[j], acc[i][j]);
    }
  }
  #pragma unroll
  for (int i = 0; i < 8; ++i) {
    const size_t row = row0 + ty * 8 + i;
    float* outp = C + row * GATES + col0 + tx * 8;
    #pragma unroll
    for (int j = 0; j < 8; ++j) outp[j] = acc[i][j] + bias[col0 + tx * 8 + j];
  }
}

// ---------------- Persistent BiLSTM recurrence ----------------
// 256 blocks x 256 threads; dir = bid&1 (disjoint CU halves run fwd/bwd
// concurrently); blk = bid>>1 owns 4 hidden units x 4 gates for all batches.
// Sync per step: every block release-stores its own flag (no RMW); the
// per-direction leader (blk 0) polls the 128 flags with 128 threads, then
// publishes 8 replicated epoch flags; followers poll ONE epoch replica with
// ONE thread. LDS h-tile uses r-stride of 9 float4s so the z-loop's 4
// r-groups per wave hit distinct bank quads (conflict-free broadcast reads).
__global__ __launch_bounds__(256, 1) void lstm_persist(
    const float* __restrict__ xzf, const float* __restrict__ xzb,
    const float* __restrict__ Rf, const float* __restrict__ Rb,
    float* __restrict__ hf, float* __restrict__ hb,
    float* __restrict__ hG,   // [2 dir][2 parity][32][512]
    int* __restrict__ flg,    // [2 dir][256 step][NBLK * FSTR]
    int* __restrict__ ep)     // [2 dir][256 step][EREP * ESTR]
{
  const int bid = blockIdx.x;
  const int dir = bid & 1;
  const int blk = bid >> 1;            // 0..127
  const int u0 = blk * UPB;
  const int tid = threadIdx.x;
  const int c = tid & 15;
  const int r = tid >> 4;
  const int gt = c & 3, uu = c >> 2;
  const int j = gt * HID + u0 + uu;    // gate-major column

  const float* __restrict__ R  = dir ? Rb : Rf;
  const float* __restrict__ xz = dir ? xzb : xzf;
  float* __restrict__ hout = dir ? hb : hf;
  float* __restrict__ hGd = hG + (size_t)dir * 2 * BB * HID;
  int* __restrict__ flgd = flg + (size_t)dir * TT * NBLK * FSTR;
  int* __restrict__ epd  = ep  + (size_t)dir * TT * EREP * ESTR;

  __shared__ float hs[BB * 144 * 4];   // 32 x 144 float4 (r-stride 9), 72 KB
  __shared__ float red[BB][4][17];
  __shared__ float zbuf[BB][20];

  // R slice in registers, natural order: Rreg[q*4+x] = R[r*32 + q*4 + x][j]
  float Rreg[32];
  #pragma unroll
  for (int q = 0; q < 8; ++q) {
    const int kb = r * 32 + q * 4;
    #pragma unroll
    for (int x = 0; x < 4; ++x)
      Rreg[q * 4 + x] = R[(size_t)(kb + x) * GATES + j];
  }

  float cst = 0.f;                     // cell state (tid<128)
  const int b_o = tid & 31, u_o = tid >> 5;
  float4* hs4 = (float4*)hs;
  const int fb0 = r, fb1 = r + 16;
  const bool leader = (blk == 0);

  for (int s = 0; s < TT; ++s) {
    const int t = dir ? (TT - 1 - s) : s;
    const int pp = (s + 1) & 1;        // parity holding h(s-1)
    const int cp = s & 1;              // parity receiving h(s)

    // prefetch xz for the finalize phase (independent of h)
    const float x0 = xz[((size_t)fb0 * TT + t) * GATES + j];
    const float x1 = xz[((size_t)fb1 * TT + t) * GATES + j];

    if (s > 0) {
      if (leader) {
        if (tid < NBLK) {
          while (!__hip_atomic_load(&flgd[((s - 1) * NBLK + tid) * FSTR],
                                    __ATOMIC_RELAXED, __HIP_MEMORY_SCOPE_AGENT))
            __builtin_amdgcn_s_sleep(1);
        }
        __syncthreads();
        __threadfence();               // acquire all blocks' h stores
        if (tid < EREP)
          __hip_atomic_store(&epd[((s - 1) * EREP + tid) * ESTR], 1,
                             __ATOMIC_RELEASE, __HIP_MEMORY_SCOPE_AGENT);
      } else {
        if (tid == 0) {
          while (!__hip_atomic_load(&epd[((s - 1) * EREP + (blk & 7)) * ESTR],
                                    __ATOMIC_RELAXED, __HIP_MEMORY_SCOPE_AGENT))
            __builtin_amdgcn_s_sleep(1);
        }
        __syncthreads();
        __threadfence();
      }
    }

    // stage h(s-1) -> LDS, padded layout slot(b,rr,kk4) = b*144 + rr*9 + kk4
    {
      const float4* hsrc = (const float4*)(hGd + (size_t)pp * BB * HID);
      #pragma unroll
      for (int q2 = 0; q2 < 16; ++q2) {
        const int gidx = tid + q2 * 256;          // float4 idx 0..4095
        const float4 v = hsrc[gidx];
        const int b = gidx >> 7, k4 = gidx & 127;
        hs4[b * 144 + (k4 >> 3) * 9 + (k4 & 7)] = v;
      }
    }
    __syncthreads();

    // z-loop: 32 batch accumulators; reads are 4-addr broadcast, conflict-free
    float z[32];
    {
      const float4* hp0 = hs4 + r * 9;
      #pragma unroll
      for (int b = 0; b < 32; ++b) {
        const float4* hp = hp0 + b * 144;
        float acc2 = 0.f;
        #pragma unroll
        for (int q = 0; q < 8; ++q) {
          const float4 hv = hp[q];
          acc2 = fmaf(hv.x, Rreg[q * 4 + 0], acc2);
          acc2 = fmaf(hv.y, Rreg[q * 4 + 1], acc2);
          acc2 = fmaf(hv.z, Rreg[q * 4 + 2], acc2);
          acc2 = fmaf(hv.w, Rreg[q * 4 + 3], acc2);
        }
        z[b] = acc2;
      }
    }

    // reduce the 4 r-slices within each wave
    #pragma unroll
    for (int b = 0; b < 32; ++b) {
      z[b] += __shfl_xor(z[b], 16);
      z[b] += __shfl_xor(z[b], 32);
    }
    {
      const int w = tid >> 6;
      if ((tid & 48) == 0) {
        #pragma unroll
        for (int b = 0; b < 32; ++b) red[b][w][c] = z[b];
      }
    }
    __syncthreads();

    // cross-wave final sum + xz
    {
      const float za = red[fb0][0][c] + red[fb0][1][c] + red[fb0][2][c] + red[fb0][3][c] + x0;
      const float zb2 = red[fb1][0][c] + red[fb1][1][c] + red[fb1][2][c] + red[fb1][3][c] + x1;
      zbuf[fb0][c] = za;
      zbuf[fb1][c] = zb2;
    }
    __syncthreads();

    if (tid < 128) {
      const float zi = zbuf[b_o][u_o * 4 + 0];
      const float zf = zbuf[b_o][u_o * 4 + 1];
      const float zg = zbuf[b_o][u_o * 4 + 2];
      const float zo = zbuf[b_o][u_o * 4 + 3];
      cst = sigf(zf) * cst + sigf(zi) * tanhf(zg);
      const float h = sigf(zo) * tanhf(cst);
      hout[((size_t)b_o * TT + t) * HID + u0 + u_o] = h;
      __hip_atomic_store(&hGd[(size_t)cp * BB * HID + b_o * HID + u0 + u_o], h,
                         __ATOMIC_RELAXED, __HIP_MEMORY_SCOPE_AGENT);
    }
    __syncthreads();
    if (tid == 0)
      __hip_atomic_store(&flgd[(s * NBLK + blk) * FSTR], 1, __ATOMIC_RELEASE,
                         __HIP_MEMORY_SCOPE_AGENT);
  }
}

// ---------------- dense + SELU ----------------
__global__ __launch_bounds__(256) void dense_selu(
    const float* __restrict__ hf, const float* __restrict__ hb,
    const float* __restrict__ W, const float* __restrict__ bias,
    float* __restrict__ out)
{
  const int bt = blockIdx.x;
  __shared__ float h[1024];
  __shared__ float part[256];
  const int tid = threadIdx.x;
  if (tid < 128) ((float4*)h)[tid] = ((const float4*)(hf + (size_t)bt * 512))[tid];
  else           ((float4*)h)[tid] = ((const float4*)(hb + (size_t)bt * 512))[tid - 128];
  __syncthreads();
  const int n = tid >> 3, s = tid & 7;
  float acc = 0.f;
  if (n < NTAG) {
    const int k0 = s * 128;
    #pragma unroll 4
    for (int k = k0; k < k0 + 128; ++k) acc = fmaf(h[k], W[(size_t)k * NTAG + n], acc);
  }
  part[tid] = acc;
  __syncthreads();
  if (tid < NTAG) {
    float v = 0.f;
    #pragma unroll
    for (int q = 0; q < 8; ++q) v += part[tid * 8 + q];
    v += bias[tid];
    const float scale = 1.0507009873554805f, alf = 1.6732632423543772f;
    v = v > 0.f ? scale * v : scale * alf * (__expf(v) - 1.f);
    out[(size_t)bt * NTAG + tid] = v;
  }
}

// ---------------- CRF NLL ----------------
__global__ __launch_bounds__(64) void crf_kernel(
    const float* __restrict__ logits,
    const int* __restrict__ tags, const int* __restrict__ lens,
    const float* __restrict__ trans, float* __restrict__ nll)
{
  const int b = blockIdx.x;
  const int tid = threadIdx.x;
  __shared__ float tr[NTAG * NTAG];
  __shared__ float al[NTAG];
  __shared__ float red[2];
  for (int i = tid; i < NTAG * NTAG; i += 64) tr[i] = trans[i];
  __syncthreads();

  int len = lens[b];
  len = len < 1 ? 1 : (len > TT ? TT : len);
  const size_t base = (size_t)b * TT;

  float us = 0.f, bs = 0.f;
  for (int t = tid; t < TT; t += 64) {
    if (t < len) us += logits[(base + t) * NTAG + tags[base + t]];
    if (t >= 1 && t < len) bs += tr[tags[base + t - 1] * NTAG + tags[base + t]];
  }
  #pragma unroll
  for (int off = 32; off > 0; off >>= 1) {
    us += __shfl_down(us, off);
    bs += __shfl_down(bs, off);
  }
  if (tid == 0) { red[0] = us; red[1] = bs; }

  if (tid < NTAG) al[tid] = logits[base * NTAG + tid];
  __syncthreads();

  for (int t = 1; t < len; ++t) {
    float nv = 0.f;
    if (tid < NTAG) {
      float m = -3.4e38f;
      #pragma unroll
      for (int i = 0; i < NTAG; ++i) m = fmaxf(m, al[i] + tr[i * NTAG + tid]);
      float ss = 0.f;
      #pragma unroll
      for (int i = 0; i < NTAG; ++i) ss += __expf(al[i] + tr[i * NTAG + tid] - m);
      nv = m + __logf(ss) + logits[(base + t) * NTAG + tid];
    }
    __syncthreads();
    if (tid < NTAG) al[tid] = nv;
    __syncthreads();
  }

  if (tid == 0) {
    float m = -3.4e38f;
    for (int i = 0; i < NTAG; ++i) m = fmaxf(m, al[i]);
    float ss = 0.f;
    for (int i = 0; i < NTAG; ++i) ss += __expf(al[i] - m);
    const float logz = m + __logf(ss);
    nll[b] = -(red[0] + red[1] - logz);
  }
}

__global__ __launch_bounds__(64) void finalize(const float* __restrict__ nll, float* __restrict__ out) {
  float v = (threadIdx.x < BB) ? nll[threadIdx.x] : 0.f;
  #pragma unroll
  for (int off = 32; off > 0; off >>= 1) v += __shfl_down(v, off);
  if (threadIdx.x == 0) out[0] = v * (1.f / BB);
}

extern "C" void kernel_launch(void* const* d_in, const int* in_sizes, int n_in,
                              void* d_out, int out_size, void* d_ws, size_t ws_size,
                              hipStream_t stream) {
  const float* emb  = (const float*)d_in[0];
  const int* tags   = (const int*)d_in[1];
  const int* lens   = (const int*)d_in[2];
  const float* kf   = (const float*)d_in[3];
  const float* rf   = (const float*)d_in[4];
  const float* bf   = (const float*)d_in[5];
  const float* kb   = (const float*)d_in[6];
  const float* rb   = (const float*)d_in[7];
  const float* bb   = (const float*)d_in[8];
  const float* dw   = (const float*)d_in[9];
  const float* db   = (const float*)d_in[10];
  const float* trans= (const float*)d_in[11];
  float* out = (float*)d_out;

  float* ws  = (float*)d_ws;
  float* xzf = ws;
  float* xzb = xzf + (size_t)BT * GATES;
  float* hf  = xzb + (size_t)BT * GATES;
  float* hb  = hf + (size_t)BT * HID;
  float* nll = hb + (size_t)BT * HID;
  float* hG  = nll + 64;                        // 2*2*32*512 = 65536 floats
  int*   flg = (int*)(hG + 2 * 2 * BB * HID);   // 2*256*128*4 = 262144 ints
  int*   ep  = flg + 2 * TT * NBLK * FSTR;      // 2*256*8*16  = 65536 ints

  // zero h-exchange buffers + flags + epochs (required every call; graph-safe)
  hipMemsetAsync(hG, 0,
                 (size_t)(2 * 2 * BB * HID + 2 * TT * NBLK * FSTR + 2 * TT * EREP * ESTR) * 4,
                 stream);

  gemm_xz<<<dim3(32, 64), 256, 0, stream>>>(emb, kf, kb, bf, bb, xzf, xzb);
  lstm_persist<<<2 * NBLK, 256, 0, stream>>>(xzf, xzb, rf, rb, hf, hb, hG, flg, ep);
  dense_selu<<<8192, 256, 0, stream>>>(hf, hb, dw, db, out + 1);
  crf_kernel<<<32, 64, 0, stream>>>(out + 1, tags, lens, trans, nll);
  finalize<<<1, 64, 0, stream>>>(nll, out);
}

// Round 5
// 3244.711 us; speedup vs baseline: 3.1896x; 2.7018x over previous
//
#include <hip/hip_runtime.h>
#include <hip/hip_bf16.h>
#include <math.h>

#define HID 512
#define GATES 2048
#define BT 8192   // 32*256
#define TT 256
#define BB 32
#define DIN 768
#define NTAG 25
#define UPB 4     // hidden units per persistent block
#define NBLK 128  // blocks per direction
#define FSTR 4    // flag stride in ints (16 B)

__device__ __forceinline__ float sigf(float x) { return 1.f / (1.f + __expf(-x)); }

// ---------------- GEMM: xz = emb @ K(dir) + bias(dir) ----------------
__global__ __launch_bounds__(256) void gemm_xz(
    const float* __restrict__ A,
    const float* __restrict__ Kf, const float* __restrict__ Kb,
    const float* __restrict__ bf, const float* __restrict__ bb,
    float* __restrict__ xzf, float* __restrict__ xzb)
{
  const int bx = blockIdx.x;   // 0..31
  const int by = blockIdx.y;   // 0..63
  const int dir = bx >> 4;
  const float* __restrict__ B = dir ? Kb : Kf;
  const float* __restrict__ bias = dir ? bb : bf;
  float* __restrict__ C = dir ? xzb : xzf;
  const int col0 = (bx & 15) * 128;
  const int row0 = by * 128;

  __shared__ float As[8][128];
  __shared__ float Bs[8][128];

  const int tid = threadIdx.x;
  const int tx = tid & 15, ty = tid >> 4;
  float acc[8][8];
  #pragma unroll
  for (int i = 0; i < 8; ++i)
    #pragma unroll
    for (int j = 0; j < 8; ++j) acc[i][j] = 0.f;

  const int arow = tid >> 1, ak4 = (tid & 1) * 4;
  const int brow = tid >> 5, bcol4 = (tid & 31) * 4;

  for (int k0 = 0; k0 < DIN; k0 += 8) {
    const float4 av = *(const float4*)(A + (size_t)(row0 + arow) * DIN + k0 + ak4);
    const float4 bv = *(const float4*)(B + (size_t)(k0 + brow) * GATES + col0 + bcol4);
    __syncthreads();
    As[ak4 + 0][arow] = av.x;
    As[ak4 + 1][arow] = av.y;
    As[ak4 + 2][arow] = av.z;
    As[ak4 + 3][arow] = av.w;
    *(float4*)&Bs[brow][bcol4] = bv;
    __syncthreads();
    #pragma unroll
    for (int kk = 0; kk < 8; ++kk) {
      float a[8], bv2[8];
      #pragma unroll
      for (int i = 0; i < 8; ++i) a[i] = As[kk][ty * 8 + i];
      #pragma unroll
      for (int j = 0; j < 8; ++j) bv2[j] = Bs[kk][tx * 8 + j];
      #pragma unroll
      for (int i = 0; i < 8; ++i)
        #pragma unroll
        for (int j = 0; j < 8; ++j) acc[i][j] = fmaf(a[i], bv2[j], acc[i][j]);
    }
  }
  #pragma unroll
  for (int i = 0; i < 8; ++i) {
    const size_t row = row0 + ty * 8 + i;
    float* outp = C + row * GATES + col0 + tx * 8;
    #pragma unroll
    for (int j = 0; j < 8; ++j) outp[j] = acc[i][j] + bias[col0 + tx * 8 + j];
  }
}

// ---------------- Persistent BiLSTM recurrence (fence-free) ----------------
// 256 blocks x 256 threads; dir = bid&1, blk = bid>>1 owns 4 hidden units x 4
// gates for all batches. h-exchange goes through hout itself: every address is
// written exactly ONCE per dispatch (write-once), via agent-scope sc1 stores
// (write-through to LLC). Readers use NORMAL cached loads: first-touch lines
// fetch from LLC (correct data), all blocks of an XCD share the L2 copy, and
// NO acquire fence / L2 invalidation is ever needed. Ordering: __syncthreads
// drains vmcnt (sc1 stores acked at LLC) before the relaxed flag store; the
// consumer's poll loop (bypass atomic loads) + barrier gives the control
// dependency.
__global__ __launch_bounds__(256, 1) void lstm_persist(
    const float* __restrict__ xzf, const float* __restrict__ xzb,
    const float* __restrict__ Rf, const float* __restrict__ Rb,
    float* __restrict__ hf, float* __restrict__ hb,
    int* __restrict__ flg)    // [2 dir][256 step][NBLK * FSTR]
{
  const int bid = blockIdx.x;
  const int dir = bid & 1;
  const int blk = bid >> 1;            // 0..127
  const int u0 = blk * UPB;
  const int tid = threadIdx.x;
  const int c = tid & 15;
  const int r = tid >> 4;
  const int gt = c & 3, uu = c >> 2;
  const int j = gt * HID + u0 + uu;    // gate-major column

  const float* __restrict__ R  = dir ? Rb : Rf;
  const float* __restrict__ xz = dir ? xzb : xzf;
  float* __restrict__ hout = dir ? hb : hf;
  int* __restrict__ flgd = flg + (size_t)dir * TT * NBLK * FSTR;

  __shared__ float hs[BB * 144 * 4];   // 32 x 144 float4 (r-stride 9), 72 KB
  __shared__ float red[BB][4][17];
  __shared__ float zbuf[BB][20];

  // R slice in registers: Rreg[q*4+x] = R[r*32 + q*4 + x][j]
  float Rreg[32];
  #pragma unroll
  for (int q = 0; q < 8; ++q) {
    const int kb = r * 32 + q * 4;
    #pragma unroll
    for (int x = 0; x < 4; ++x)
      Rreg[q * 4 + x] = R[(size_t)(kb + x) * GATES + j];
  }

  float cst = 0.f;                     // cell state (tid<128)
  const int b_o = tid & 31, u_o = tid >> 5;
  float4* hs4 = (float4*)hs;
  const int fb0 = r, fb1 = r + 16;
  const float4* __restrict__ hsrc = (const float4*)hout;

  for (int s = 0; s < TT; ++s) {
    const int t = dir ? (TT - 1 - s) : s;

    // prefetch xz for the finalize phase (independent of h)
    const float x0 = xz[((size_t)fb0 * TT + t) * GATES + j];
    const float x1 = xz[((size_t)fb1 * TT + t) * GATES + j];

    if (s > 0) {
      const int tprev = dir ? t + 1 : t - 1;
      if (tid < NBLK) {
        while (!__hip_atomic_load(&flgd[((s - 1) * NBLK + tid) * FSTR],
                                  __ATOMIC_RELAXED, __HIP_MEMORY_SCOPE_AGENT))
          __builtin_amdgcn_s_sleep(2);
      }
      __syncthreads();
      // stage h(s-1) from hout (normal cached loads; first-touch lines)
      #pragma unroll
      for (int q2 = 0; q2 < 16; ++q2) {
        const int gidx = tid + q2 * 256;          // float4 idx 0..4095
        const int b = gidx >> 7, k4 = gidx & 127;
        const float4 v = hsrc[(size_t)(b * TT + tprev) * (HID / 4) + k4];
        hs4[b * 144 + (k4 >> 3) * 9 + (k4 & 7)] = v;
      }
    } else {
      const float4 zz = make_float4(0.f, 0.f, 0.f, 0.f);
      #pragma unroll
      for (int q2 = 0; q2 < 16; ++q2) {
        const int gidx = tid + q2 * 256;
        const int b = gidx >> 7, k4 = gidx & 127;
        hs4[b * 144 + (k4 >> 3) * 9 + (k4 & 7)] = zz;
      }
    }
    __syncthreads();

    // z-loop: 32 batch accumulators; 4-addr broadcast reads, conflict-free
    float z[32];
    {
      const float4* hp0 = hs4 + r * 9;
      #pragma unroll
      for (int b = 0; b < 32; ++b) {
        const float4* hp = hp0 + b * 144;
        float acc2 = 0.f;
        #pragma unroll
        for (int q = 0; q < 8; ++q) {
          const float4 hv = hp[q];
          acc2 = fmaf(hv.x, Rreg[q * 4 + 0], acc2);
          acc2 = fmaf(hv.y, Rreg[q * 4 + 1], acc2);
          acc2 = fmaf(hv.z, Rreg[q * 4 + 2], acc2);
          acc2 = fmaf(hv.w, Rreg[q * 4 + 3], acc2);
        }
        z[b] = acc2;
      }
    }

    // reduce the 4 r-slices within each wave
    #pragma unroll
    for (int b = 0; b < 32; ++b) {
      z[b] += __shfl_xor(z[b], 16);
      z[b] += __shfl_xor(z[b], 32);
    }
    {
      const int w = tid >> 6;
      if ((tid & 48) == 0) {
        #pragma unroll
        for (int b = 0; b < 32; ++b) red[b][w][c] = z[b];
      }
    }
    __syncthreads();

    // cross-wave final sum + xz
    {
      const float za = red[fb0][0][c] + red[fb0][1][c] + red[fb0][2][c] + red[fb0][3][c] + x0;
      const float zb2 = red[fb1][0][c] + red[fb1][1][c] + red[fb1][2][c] + red[fb1][3][c] + x1;
      zbuf[fb0][c] = za;
      zbuf[fb1][c] = zb2;
    }
    __syncthreads();

    if (tid < 128) {
      const float zi = zbuf[b_o][u_o * 4 + 0];
      const float zf = zbuf[b_o][u_o * 4 + 1];
      const float zg = zbuf[b_o][u_o * 4 + 2];
      const float zo = zbuf[b_o][u_o * 4 + 3];
      cst = sigf(zf) * cst + sigf(zi) * tanhf(zg);
      const float h = sigf(zo) * tanhf(cst);
      // write-through to LLC; this IS both the output and the h-exchange
      __hip_atomic_store(&hout[((size_t)b_o * TT + t) * HID + u0 + u_o], h,
                         __ATOMIC_RELAXED, __HIP_MEMORY_SCOPE_AGENT);
    }
    __syncthreads();   // drains each wave's vmcnt => h stores acked at LLC
    if (tid == 0)
      __hip_atomic_store(&flgd[(s * NBLK + blk) * FSTR], 1, __ATOMIC_RELAXED,
                         __HIP_MEMORY_SCOPE_AGENT);
  }
}

// ---------------- dense + SELU ----------------
__global__ __launch_bounds__(256) void dense_selu(
    const float* __restrict__ hf, const float* __restrict__ hb,
    const float* __restrict__ W, const float* __restrict__ bias,
    float* __restrict__ out)
{
  const int bt = blockIdx.x;
  __shared__ float h[1024];
  __shared__ float part[256];
  const int tid = threadIdx.x;
  if (tid < 128) ((float4*)h)[tid] = ((const float4*)(hf + (size_t)bt * 512))[tid];
  else           ((float4*)h)[tid] = ((const float4*)(hb + (size_t)bt * 512))[tid - 128];
  __syncthreads();
  const int n = tid >> 3, s = tid & 7;
  float acc = 0.f;
  if (n < NTAG) {
    const int k0 = s * 128;
    #pragma unroll 4
    for (int k = k0; k < k0 + 128; ++k) acc = fmaf(h[k], W[(size_t)k * NTAG + n], acc);
  }
  part[tid] = acc;
  __syncthreads();
  if (tid < NTAG) {
    float v = 0.f;
    #pragma unroll
    for (int q = 0; q < 8; ++q) v += part[tid * 8 + q];
    v += bias[tid];
    const float scale = 1.0507009873554805f, alf = 1.6732632423543772f;
    v = v > 0.f ? scale * v : scale * alf * (__expf(v) - 1.f);
    out[(size_t)bt * NTAG + tid] = v;
  }
}

// ---------------- CRF NLL ----------------
__global__ __launch_bounds__(64) void crf_kernel(
    const float* __restrict__ logits,
    const int* __restrict__ tags, const int* __restrict__ lens,
    const float* __restrict__ trans, float* __restrict__ nll)
{
  const int b = blockIdx.x;
  const int tid = threadIdx.x;
  __shared__ float tr[NTAG * NTAG];
  __shared__ float al[NTAG];
  __shared__ float red[2];
  for (int i = tid; i < NTAG * NTAG; i += 64) tr[i] = trans[i];
  __syncthreads();

  int len = lens[b];
  len = len < 1 ? 1 : (len > TT ? TT : len);
  const size_t base = (size_t)b * TT;

  float us = 0.f, bs = 0.f;
  for (int t = tid; t < TT; t += 64) {
    if (t < len) us += logits[(base + t) * NTAG + tags[base + t]];
    if (t >= 1 && t < len) bs += tr[tags[base + t - 1] * NTAG + tags[base + t]];
  }
  #pragma unroll
  for (int off = 32; off > 0; off >>= 1) {
    us += __shfl_down(us, off);
    bs += __shfl_down(bs, off);
  }
  if (tid == 0) { red[0] = us; red[1] = bs; }

  if (tid < NTAG) al[tid] = logits[base * NTAG + tid];
  __syncthreads();

  for (int t = 1; t < len; ++t) {
    float nv = 0.f;
    if (tid < NTAG) {
      float m = -3.4e38f;
      #pragma unroll
      for (int i = 0; i < NTAG; ++i) m = fmaxf(m, al[i] + tr[i * NTAG + tid]);
      float ss = 0.f;
      #pragma unroll
      for (int i = 0; i < NTAG; ++i) ss += __expf(al[i] + tr[i * NTAG + tid] - m);
      nv = m + __logf(ss) + logits[(base + t) * NTAG + tid];
    }
    __syncthreads();
    if (tid < NTAG) al[tid] = nv;
    __syncthreads();
  }

  if (tid == 0) {
    float m = -3.4e38f;
    for (int i = 0; i < NTAG; ++i) m = fmaxf(m, al[i]);
    float ss = 0.f;
    for (int i = 0; i < NTAG; ++i) ss += __expf(al[i] - m);
    const float logz = m + __logf(ss);
    nll[b] = -(red[0] + red[1] - logz);
  }
}

__global__ __launch_bounds__(64) void finalize(const float* __restrict__ nll, float* __restrict__ out) {
  float v = (threadIdx.x < BB) ? nll[threadIdx.x] : 0.f;
  #pragma unroll
  for (int off = 32; off > 0; off >>= 1) v += __shfl_down(v, off);
  if (threadIdx.x == 0) out[0] = v * (1.f / BB);
}

extern "C" void kernel_launch(void* const* d_in, const int* in_sizes, int n_in,
                              void* d_out, int out_size, void* d_ws, size_t ws_size,
                              hipStream_t stream) {
  const float* emb  = (const float*)d_in[0];
  const int* tags   = (const int*)d_in[1];
  const int* lens   = (const int*)d_in[2];
  const float* kf   = (const float*)d_in[3];
  const float* rf   = (const float*)d_in[4];
  const float* bf   = (const float*)d_in[5];
  const float* kb   = (const float*)d_in[6];
  const float* rb   = (const float*)d_in[7];
  const float* bb   = (const float*)d_in[8];
  const float* dw   = (const float*)d_in[9];
  const float* db   = (const float*)d_in[10];
  const float* trans= (const float*)d_in[11];
  float* out = (float*)d_out;

  float* ws  = (float*)d_ws;
  float* xzf = ws;
  float* xzb = xzf + (size_t)BT * GATES;
  float* hf  = xzb + (size_t)BT * GATES;
  float* hb  = hf + (size_t)BT * HID;
  float* nll = hb + (size_t)BT * HID;
  int*   flg = (int*)(nll + 64);               // 2*256*128*4 = 262144 ints

  // zero the step flags (required every call; graph-safe)
  hipMemsetAsync(flg, 0, (size_t)(2 * TT * NBLK * FSTR) * 4, stream);

  gemm_xz<<<dim3(32, 64), 256, 0, stream>>>(emb, kf, kb, bf, bb, xzf, xzb);
  lstm_persist<<<2 * NBLK, 256, 0, stream>>>(xzf, xzb, rf, rb, hf, hb, flg);
  dense_selu<<<8192, 256, 0, stream>>>(hf, hb, dw, db, out + 1);
  crf_kernel<<<32, 64, 0, stream>>>(out + 1, tags, lens, trans, nll);
  finalize<<<1, 64, 0, stream>>>(nll, out);
}

// Round 6
// 3061.245 us; speedup vs baseline: 3.3807x; 1.0599x over previous
//
#include <hip/hip_runtime.h>
#include <hip/hip_bf16.h>
#include <math.h>

#define HID 512
#define GATES 2048
#define BT 8192   // 32*256
#define TT 256
#define BB 32
#define DIN 768
#define NTAG 25
#define UPB 4     // hidden units per persistent block
#define NBLK 128  // blocks per direction
#define FSTR 4    // flag stride in ints (16 B)
#define EREP 8    // epoch flag replicas
#define ESTR 16   // epoch replica stride in ints (64 B)

__device__ __forceinline__ float sigf(float x) { return 1.f / (1.f + __expf(-x)); }

// ---------------- GEMM: xz = emb @ K(dir) + bias(dir) ----------------
__global__ __launch_bounds__(256) void gemm_xz(
    const float* __restrict__ A,
    const float* __restrict__ Kf, const float* __restrict__ Kb,
    const float* __restrict__ bf, const float* __restrict__ bb,
    float* __restrict__ xzf, float* __restrict__ xzb)
{
  const int bx = blockIdx.x;   // 0..31
  const int by = blockIdx.y;   // 0..63
  const int dir = bx >> 4;
  const float* __restrict__ B = dir ? Kb : Kf;
  const float* __restrict__ bias = dir ? bb : bf;
  float* __restrict__ C = dir ? xzb : xzf;
  const int col0 = (bx & 15) * 128;
  const int row0 = by * 128;

  __shared__ float As[8][128];
  __shared__ float Bs[8][128];

  const int tid = threadIdx.x;
  const int tx = tid & 15, ty = tid >> 4;
  float acc[8][8];
  #pragma unroll
  for (int i = 0; i < 8; ++i)
    #pragma unroll
    for (int j = 0; j < 8; ++j) acc[i][j] = 0.f;

  const int arow = tid >> 1, ak4 = (tid & 1) * 4;
  const int brow = tid >> 5, bcol4 = (tid & 31) * 4;

  for (int k0 = 0; k0 < DIN; k0 += 8) {
    const float4 av = *(const float4*)(A + (size_t)(row0 + arow) * DIN + k0 + ak4);
    const float4 bv = *(const float4*)(B + (size_t)(k0 + brow) * GATES + col0 + bcol4);
    __syncthreads();
    As[ak4 + 0][arow] = av.x;
    As[ak4 + 1][arow] = av.y;
    As[ak4 + 2][arow] = av.z;
    As[ak4 + 3][arow] = av.w;
    *(float4*)&Bs[brow][bcol4] = bv;
    __syncthreads();
    #pragma unroll
    for (int kk = 0; kk < 8; ++kk) {
      float a[8], bv2[8];
      #pragma unroll
      for (int i = 0; i < 8; ++i) a[i] = As[kk][ty * 8 + i];
      #pragma unroll
      for (int j = 0; j < 8; ++j) bv2[j] = Bs[kk][tx * 8 + j];
      #pragma unroll
      for (int i = 0; i < 8; ++i)
        #pragma unroll
        for (int j = 0; j < 8; ++j) acc[i][j] = fmaf(a[i], bv2[j], acc[i][j]);
    }
  }
  #pragma unroll
  for (int i = 0; i < 8; ++i) {
    const size_t row = row0 + ty * 8 + i;
    float* outp = C + row * GATES + col0 + tx * 8;
    #pragma unroll
    for (int j = 0; j < 8; ++j) outp[j] = acc[i][j] + bias[col0 + tx * 8 + j];
  }
}

// ---------------- Persistent BiLSTM recurrence (fence-free, tree sync) ------
// 256 blocks x 256 threads; dir = bid&1, blk = bid>>1 owns 4 hidden units x 4
// gates for all batches. h-exchange goes through hout (write-once addresses,
// agent-scope sc1 stores); readers use normal cached first-touch loads -> no
// acquire fence ever. Sync tree per step (fence-free): producers release-store
// their own 16B-strided flag; ONLY the per-direction leader block polls the
// 128 flags (128 threads); leader publishes 8 replicated epoch lines BEFORE
// staging; followers poll ONE epoch replica with ONE thread. Poller count
// ~260 vs 32K flat -- kills the LLC poll storm seen as FETCH_SIZE inflation.
__global__ __launch_bounds__(256, 1) void lstm_persist(
    const float* __restrict__ xzf, const float* __restrict__ xzb,
    const float* __restrict__ Rf, const float* __restrict__ Rb,
    float* __restrict__ hf, float* __restrict__ hb,
    int* __restrict__ flg,    // [2 dir][256 step][NBLK * FSTR]
    int* __restrict__ ep)     // [2 dir][256 step][EREP * ESTR]
{
  const int bid = blockIdx.x;
  const int dir = bid & 1;
  const int blk = bid >> 1;            // 0..127
  const int u0 = blk * UPB;
  const int tid = threadIdx.x;
  const int c = tid & 15;
  const int r = tid >> 4;
  const int gt = c & 3, uu = c >> 2;
  const int j = gt * HID + u0 + uu;    // gate-major column

  const float* __restrict__ R  = dir ? Rb : Rf;
  const float* __restrict__ xz = dir ? xzb : xzf;
  float* __restrict__ hout = dir ? hb : hf;
  int* __restrict__ flgd = flg + (size_t)dir * TT * NBLK * FSTR;
  int* __restrict__ epd  = ep  + (size_t)dir * TT * EREP * ESTR;

  __shared__ float hs[BB * 144 * 4];   // 32 x 144 float4 (r-stride 9), 72 KB
  __shared__ float red[BB][4][17];
  __shared__ float zbuf[BB][20];

  // R slice in registers: Rreg[q*4+x] = R[r*32 + q*4 + x][j]
  float Rreg[32];
  #pragma unroll
  for (int q = 0; q < 8; ++q) {
    const int kb = r * 32 + q * 4;
    #pragma unroll
    for (int x = 0; x < 4; ++x)
      Rreg[q * 4 + x] = R[(size_t)(kb + x) * GATES + j];
  }

  float cst = 0.f;                     // cell state (tid<128)
  const int b_o = tid & 31, u_o = tid >> 5;
  float4* hs4 = (float4*)hs;
  const int fb0 = r, fb1 = r + 16;
  const float4* __restrict__ hsrc = (const float4*)hout;
  const bool leader = (blk == 0);

  for (int s = 0; s < TT; ++s) {
    const int t = dir ? (TT - 1 - s) : s;

    // prefetch xz for the finalize phase (overlaps the poll)
    const float x0 = xz[((size_t)fb0 * TT + t) * GATES + j];
    const float x1 = xz[((size_t)fb1 * TT + t) * GATES + j];

    if (s > 0) {
      const int tprev = dir ? t + 1 : t - 1;
      if (leader) {
        if (tid < NBLK) {
          while (!__hip_atomic_load(&flgd[((s - 1) * NBLK + tid) * FSTR],
                                    __ATOMIC_RELAXED, __HIP_MEMORY_SCOPE_AGENT))
            __builtin_amdgcn_s_sleep(1);
        }
        __syncthreads();
        if (tid < EREP)   // publish BEFORE staging so followers unblock now
          __hip_atomic_store(&epd[((s - 1) * EREP + tid) * ESTR], 1,
                             __ATOMIC_RELAXED, __HIP_MEMORY_SCOPE_AGENT);
      } else {
        if (tid == 0) {
          while (!__hip_atomic_load(&epd[((s - 1) * EREP + (blk & 7)) * ESTR],
                                    __ATOMIC_RELAXED, __HIP_MEMORY_SCOPE_AGENT))
            __builtin_amdgcn_s_sleep(1);
        }
        __syncthreads();
      }
      // stage h(s-1) from hout (normal cached loads; first-touch lines)
      #pragma unroll
      for (int q2 = 0; q2 < 16; ++q2) {
        const int gidx = tid + q2 * 256;          // float4 idx 0..4095
        const int b = gidx >> 7, k4 = gidx & 127;
        const float4 v = hsrc[(size_t)(b * TT + tprev) * (HID / 4) + k4];
        hs4[b * 144 + (k4 >> 3) * 9 + (k4 & 7)] = v;
      }
    } else {
      const float4 zz = make_float4(0.f, 0.f, 0.f, 0.f);
      #pragma unroll
      for (int q2 = 0; q2 < 16; ++q2) {
        const int gidx = tid + q2 * 256;
        const int b = gidx >> 7, k4 = gidx & 127;
        hs4[b * 144 + (k4 >> 3) * 9 + (k4 & 7)] = zz;
      }
    }
    __syncthreads();

    // z-loop: 32 batch accumulators; 4-addr broadcast reads, conflict-free
    float z[32];
    {
      const float4* hp0 = hs4 + r * 9;
      #pragma unroll
      for (int b = 0; b < 32; ++b) {
        const float4* hp = hp0 + b * 144;
        float acc2 = 0.f;
        #pragma unroll
        for (int q = 0; q < 8; ++q) {
          const float4 hv = hp[q];
          acc2 = fmaf(hv.x, Rreg[q * 4 + 0], acc2);
          acc2 = fmaf(hv.y, Rreg[q * 4 + 1], acc2);
          acc2 = fmaf(hv.z, Rreg[q * 4 + 2], acc2);
          acc2 = fmaf(hv.w, Rreg[q * 4 + 3], acc2);
        }
        z[b] = acc2;
      }
    }

    // reduce the 4 r-slices within each wave
    #pragma unroll
    for (int b = 0; b < 32; ++b) {
      z[b] += __shfl_xor(z[b], 16);
      z[b] += __shfl_xor(z[b], 32);
    }
    {
      const int w = tid >> 6;
      if ((tid & 48) == 0) {
        #pragma unroll
        for (int b = 0; b < 32; ++b) red[b][w][c] = z[b];
      }
    }
    __syncthreads();

    // cross-wave final sum + xz
    {
      const float za = red[fb0][0][c] + red[fb0][1][c] + red[fb0][2][c] + red[fb0][3][c] + x0;
      const float zb2 = red[fb1][0][c] + red[fb1][1][c] + red[fb1][2][c] + red[fb1][3][c] + x1;
      zbuf[fb0][c] = za;
      zbuf[fb1][c] = zb2;
    }
    __syncthreads();

    if (tid < 128) {
      const float zi = zbuf[b_o][u_o * 4 + 0];
      const float zf = zbuf[b_o][u_o * 4 + 1];
      const float zg = zbuf[b_o][u_o * 4 + 2];
      const float zo = zbuf[b_o][u_o * 4 + 3];
      cst = sigf(zf) * cst + sigf(zi) * tanhf(zg);
      const float h = sigf(zo) * tanhf(cst);
      // write-through to LLC; this IS both the output and the h-exchange
      __hip_atomic_store(&hout[((size_t)b_o * TT + t) * HID + u0 + u_o], h,
                         __ATOMIC_RELAXED, __HIP_MEMORY_SCOPE_AGENT);
    }
    __syncthreads();   // drains each wave's vmcnt => h stores acked at LLC
    if (tid == 0)
      __hip_atomic_store(&flgd[(s * NBLK + blk) * FSTR], 1, __ATOMIC_RELAXED,
                         __HIP_MEMORY_SCOPE_AGENT);
  }
}

// ---------------- dense + SELU ----------------
__global__ __launch_bounds__(256) void dense_selu(
    const float* __restrict__ hf, const float* __restrict__ hb,
    const float* __restrict__ W, const float* __restrict__ bias,
    float* __restrict__ out)
{
  const int bt = blockIdx.x;
  __shared__ float h[1024];
  __shared__ float part[256];
  const int tid = threadIdx.x;
  if (tid < 128) ((float4*)h)[tid] = ((const float4*)(hf + (size_t)bt * 512))[tid];
  else           ((float4*)h)[tid] = ((const float4*)(hb + (size_t)bt * 512))[tid - 128];
  __syncthreads();
  const int n = tid >> 3, s = tid & 7;
  float acc = 0.f;
  if (n < NTAG) {
    const int k0 = s * 128;
    #pragma unroll 4
    for (int k = k0; k < k0 + 128; ++k) acc = fmaf(h[k], W[(size_t)k * NTAG + n], acc);
  }
  part[tid] = acc;
  __syncthreads();
  if (tid < NTAG) {
    float v = 0.f;
    #pragma unroll
    for (int q = 0; q < 8; ++q) v += part[tid * 8 + q];
    v += bias[tid];
    const float scale = 1.0507009873554805f, alf = 1.6732632423543772f;
    v = v > 0.f ? scale * v : scale * alf * (__expf(v) - 1.f);
    out[(size_t)bt * NTAG + tid] = v;
  }
}

// ---------------- CRF NLL ----------------
__global__ __launch_bounds__(64) void crf_kernel(
    const float* __restrict__ logits,
    const int* __restrict__ tags, const int* __restrict__ lens,
    const float* __restrict__ trans, float* __restrict__ nll)
{
  const int b = blockIdx.x;
  const int tid = threadIdx.x;
  __shared__ float tr[NTAG * NTAG];
  __shared__ float al[NTAG];
  __shared__ float red[2];
  for (int i = tid; i < NTAG * NTAG; i += 64) tr[i] = trans[i];
  __syncthreads();

  int len = lens[b];
  len = len < 1 ? 1 : (len > TT ? TT : len);
  const size_t base = (size_t)b * TT;

  float us = 0.f, bs = 0.f;
  for (int t = tid; t < TT; t += 64) {
    if (t < len) us += logits[(base + t) * NTAG + tags[base + t]];
    if (t >= 1 && t < len) bs += tr[tags[base + t - 1] * NTAG + tags[base + t]];
  }
  #pragma unroll
  for (int off = 32; off > 0; off >>= 1) {
    us += __shfl_down(us, off);
    bs += __shfl_down(bs, off);
  }
  if (tid == 0) { red[0] = us; red[1] = bs; }

  if (tid < NTAG) al[tid] = logits[base * NTAG + tid];
  __syncthreads();

  for (int t = 1; t < len; ++t) {
    float nv = 0.f;
    if (tid < NTAG) {
      float m = -3.4e38f;
      #pragma unroll
      for (int i = 0; i < NTAG; ++i) m = fmaxf(m, al[i] + tr[i * NTAG + tid]);
      float ss = 0.f;
      #pragma unroll
      for (int i = 0; i < NTAG; ++i) ss += __expf(al[i] + tr[i * NTAG + tid] - m);
      nv = m + __logf(ss) + logits[(base + t) * NTAG + tid];
    }
    __syncthreads();
    if (tid < NTAG) al[tid] = nv;
    __syncthreads();
  }

  if (tid == 0) {
    float m = -3.4e38f;
    for (int i = 0; i < NTAG; ++i) m = fmaxf(m, al[i]);
    float ss = 0.f;
    for (int i = 0; i < NTAG; ++i) ss += __expf(al[i] - m);
    const float logz = m + __logf(ss);
    nll[b] = -(red[0] + red[1] - logz);
  }
}

__global__ __launch_bounds__(64) void finalize(const float* __restrict__ nll, float* __restrict__ out) {
  float v = (threadIdx.x < BB) ? nll[threadIdx.x] : 0.f;
  #pragma unroll
  for (int off = 32; off > 0; off >>= 1) v += __shfl_down(v, off);
  if (threadIdx.x == 0) out[0] = v * (1.f / BB);
}

extern "C" void kernel_launch(void* const* d_in, const int* in_sizes, int n_in,
                              void* d_out, int out_size, void* d_ws, size_t ws_size,
                              hipStream_t stream) {
  const float* emb  = (const float*)d_in[0];
  const int* tags   = (const int*)d_in[1];
  const int* lens   = (const int*)d_in[2];
  const float* kf   = (const float*)d_in[3];
  const float* rf   = (const float*)d_in[4];
  const float* bf   = (const float*)d_in[5];
  const float* kb   = (const float*)d_in[6];
  const float* rb   = (const float*)d_in[7];
  const float* bb   = (const float*)d_in[8];
  const float* dw   = (const float*)d_in[9];
  const float* db   = (const float*)d_in[10];
  const float* trans= (const float*)d_in[11];
  float* out = (float*)d_out;

  float* ws  = (float*)d_ws;
  float* xzf = ws;
  float* xzb = xzf + (size_t)BT * GATES;
  float* hf  = xzb + (size_t)BT * GATES;
  float* hb  = hf + (size_t)BT * HID;
  float* nll = hb + (size_t)BT * HID;
  int*   flg = (int*)(nll + 64);               // 2*256*128*4 = 262144 ints
  int*   ep  = flg + 2 * TT * NBLK * FSTR;     // 2*256*8*16  = 65536 ints

  // zero the step flags + epochs (required every call; graph-safe)
  hipMemsetAsync(flg, 0, (size_t)(2 * TT * NBLK * FSTR + 2 * TT * EREP * ESTR) * 4,
                 stream);

  gemm_xz<<<dim3(32, 64), 256, 0, stream>>>(emb, kf, kb, bf, bb, xzf, xzb);
  lstm_persist<<<2 * NBLK, 256, 0, stream>>>(xzf, xzb, rf, rb, hf, hb, flg, ep);
  dense_selu<<<8192, 256, 0, stream>>>(hf, hb, dw, db, out + 1);
  crf_kernel<<<32, 64, 0, stream>>>(out + 1, tags, lens, trans, nll);
  finalize<<<1, 64, 0, stream>>>(nll, out);
}

// Round 8
// 2218.898 us; speedup vs baseline: 4.6642x; 1.3796x over previous
//
#include <hip/hip_runtime.h>
#include <hip/hip_bf16.h>
#include <math.h>

#define HID 512
#define GATES 2048
#define BT 8192   // 32*256
#define TT 256
#define BB 32
#define DIN 768
#define NTAG 25
#define UPB 4     // hidden units per persistent block
#define NBLK 128  // blocks per direction
#define FSTR 4    // flag stride in ints (16 B)
#define EREP 8    // epoch flag replicas
#define ESTR 16   // epoch replica stride in ints (64 B)

typedef _Float16 half2v __attribute__((ext_vector_type(2)));

__device__ __forceinline__ half2v pack2h(float a, float b) {
  return __builtin_bit_cast(half2v, __builtin_amdgcn_cvt_pkrtz(a, b));
}

__device__ __forceinline__ float sigf(float x) { return 1.f / (1.f + __expf(-x)); }

// ---------------- GEMM: xz = emb @ K(dir) + bias(dir) ----------------
__global__ __launch_bounds__(256) void gemm_xz(
    const float* __restrict__ A,
    const float* __restrict__ Kf, const float* __restrict__ Kb,
    const float* __restrict__ bf, const float* __restrict__ bb,
    float* __restrict__ xzf, float* __restrict__ xzb)
{
  const int bx = blockIdx.x;   // 0..31
  const int by = blockIdx.y;   // 0..63
  const int dir = bx >> 4;
  const float* __restrict__ B = dir ? Kb : Kf;
  const float* __restrict__ bias = dir ? bb : bf;
  float* __restrict__ C = dir ? xzb : xzf;
  const int col0 = (bx & 15) * 128;
  const int row0 = by * 128;

  __shared__ float As[8][128];
  __shared__ float Bs[8][128];

  const int tid = threadIdx.x;
  const int tx = tid & 15, ty = tid >> 4;
  float acc[8][8];
  #pragma unroll
  for (int i = 0; i < 8; ++i)
    #pragma unroll
    for (int j = 0; j < 8; ++j) acc[i][j] = 0.f;

  const int arow = tid >> 1, ak4 = (tid & 1) * 4;
  const int brow = tid >> 5, bcol4 = (tid & 31) * 4;

  for (int k0 = 0; k0 < DIN; k0 += 8) {
    const float4 av = *(const float4*)(A + (size_t)(row0 + arow) * DIN + k0 + ak4);
    const float4 bv = *(const float4*)(B + (size_t)(k0 + brow) * GATES + col0 + bcol4);
    __syncthreads();
    As[ak4 + 0][arow] = av.x;
    As[ak4 + 1][arow] = av.y;
    As[ak4 + 2][arow] = av.z;
    As[ak4 + 3][arow] = av.w;
    *(float4*)&Bs[brow][bcol4] = bv;
    __syncthreads();
    #pragma unroll
    for (int kk = 0; kk < 8; ++kk) {
      float a[8], bv2[8];
      #pragma unroll
      for (int i = 0; i < 8; ++i) a[i] = As[kk][ty * 8 + i];
      #pragma unroll
      for (int j = 0; j < 8; ++j) bv2[j] = Bs[kk][tx * 8 + j];
      #pragma unroll
      for (int i = 0; i < 8; ++i)
        #pragma unroll
        for (int j = 0; j < 8; ++j) acc[i][j] = fmaf(a[i], bv2[j], acc[i][j]);
    }
  }
  #pragma unroll
  for (int i = 0; i < 8; ++i) {
    const size_t row = row0 + ty * 8 + i;
    float* outp = C + row * GATES + col0 + tx * 8;
    #pragma unroll
    for (int j = 0; j < 8; ++j) outp[j] = acc[i][j] + bias[col0 + tx * 8 + j];
  }
}

// ---------------- Persistent BiLSTM (fence-free, f16 data path) ----------
// 256 blocks x 256 threads; dir = bid&1, blk = bid>>1 owns 4 hidden units x 4
// gates for all batches. h is exchanged as PACKED F16 pairs through
// hG[dir][t][b][256 dwords] -- write-once addresses, agent-scope stores,
// normal cached first-touch reads => no acquire fences. z-loop uses
// v_dot2_f32_f16 (f16 inputs, fp32 accumulate). LDS h-tile: chunk stride 20
// dwords so the wave's 4 r-groups hit disjoint bank quads (conflict-free).
// Sync: producers release-store own flag; per-direction leader polls all 128,
// publishes 8 replicated epoch lines; followers poll one replica.
__global__ __launch_bounds__(256, 1) void lstm_persist(
    const float* __restrict__ xzf, const float* __restrict__ xzb,
    const float* __restrict__ Rf, const float* __restrict__ Rb,
    unsigned int* __restrict__ hGf, unsigned int* __restrict__ hGb,
    int* __restrict__ flg,    // [2 dir][256 step][NBLK * FSTR]
    int* __restrict__ ep)     // [2 dir][256 step][EREP * ESTR]
{
  const int bid = blockIdx.x;
  const int dir = bid & 1;
  const int blk = bid >> 1;            // 0..127
  const int u0 = blk * UPB;
  const int tid = threadIdx.x;
  const int c = tid & 15;
  const int r = tid >> 4;              // 0..15: k-slice [r*32, r*32+32)
  const int gt = c & 3, uu = c >> 2;
  const int j = gt * HID + u0 + uu;    // gate-major column

  const float* __restrict__ R  = dir ? Rb : Rf;
  const float* __restrict__ xz = dir ? xzb : xzf;
  unsigned int* __restrict__ hGd = dir ? hGb : hGf;
  int* __restrict__ flgd = flg + (size_t)dir * TT * NBLK * FSTR;
  int* __restrict__ epd  = ep  + (size_t)dir * TT * EREP * ESTR;

  // h tile: 32 b x 16 chunks x 20 dwords (16 data + 4 pad) = 40 KB
  __shared__ unsigned int hsw[BB * 320];
  __shared__ float red[BB][4][17];
  __shared__ float zbuf[BB][20];

  // R slice as f16 pairs: Rh[m] = (R[r*32+2m][j], R[r*32+2m+1][j])
  half2v Rh[16];
  #pragma unroll
  for (int m = 0; m < 16; ++m) {
    const int k = r * 32 + 2 * m;
    const float f0 = R[(size_t)k * GATES + j];
    const float f1 = R[(size_t)(k + 1) * GATES + j];
    Rh[m] = pack2h(f0, f1);
  }

  float cst = 0.f;                     // cell state (tid<128)
  const int b_o = tid & 31, u_o = tid >> 5;
  uint4* hs4 = (uint4*)hsw;
  const int fb0 = r, fb1 = r + 16;
  const bool leader = (blk == 0);

  for (int s = 0; s < TT; ++s) {
    const int t = dir ? (TT - 1 - s) : s;

    // prefetch xz for the finalize phase (overlaps the poll)
    const float x0 = xz[((size_t)fb0 * TT + t) * GATES + j];
    const float x1 = xz[((size_t)fb1 * TT + t) * GATES + j];

    if (s > 0) {
      const int tprev = dir ? t + 1 : t - 1;
      if (leader) {
        if (tid < NBLK) {
          while (!__hip_atomic_load(&flgd[((s - 1) * NBLK + tid) * FSTR],
                                    __ATOMIC_RELAXED, __HIP_MEMORY_SCOPE_AGENT))
            __builtin_amdgcn_s_sleep(1);
        }
        __syncthreads();
        if (tid < EREP)   // publish BEFORE staging so followers unblock now
          __hip_atomic_store(&epd[((s - 1) * EREP + tid) * ESTR], 1,
                             __ATOMIC_RELAXED, __HIP_MEMORY_SCOPE_AGENT);
      } else {
        if (tid == 0) {
          while (!__hip_atomic_load(&epd[((s - 1) * EREP + (blk & 7)) * ESTR],
                                    __ATOMIC_RELAXED, __HIP_MEMORY_SCOPE_AGENT))
            __builtin_amdgcn_s_sleep(1);
        }
        __syncthreads();
      }
      // stage packed-f16 h(s-1) -> LDS (2048 uint4 total, 8 per thread)
      const uint4* hsrc = (const uint4*)(hGd + (size_t)tprev * BB * 256);
      #pragma unroll
      for (int it = 0; it < 8; ++it) {
        const int g4 = tid + it * 256;
        const uint4 v = hsrc[g4];
        const int b = g4 >> 6, rem = g4 & 63;
        hs4[b * 80 + (rem >> 2) * 5 + (rem & 3)] = v;
      }
    } else {
      const uint4 zz = make_uint4(0u, 0u, 0u, 0u);
      #pragma unroll
      for (int it = 0; it < 10; ++it)
        hs4[tid + it * 256] = zz;
    }
    __syncthreads();

    // z-loop: 32 batch accumulators; 4 ds_read_b128 + 16 fdot2 per batch
    float z[32];
    {
      const uint4* hp0 = hs4 + r * 5;
      #pragma unroll
      for (int b = 0; b < 32; ++b) {
        const uint4* hp = hp0 + b * 80;
        float acc2 = 0.f;
        #pragma unroll
        for (int q = 0; q < 4; ++q) {
          const uint4 v = hp[q];
          acc2 = __builtin_amdgcn_fdot2(__builtin_bit_cast(half2v, v.x), Rh[q * 4 + 0], acc2, false);
          acc2 = __builtin_amdgcn_fdot2(__builtin_bit_cast(half2v, v.y), Rh[q * 4 + 1], acc2, false);
          acc2 = __builtin_amdgcn_fdot2(__builtin_bit_cast(half2v, v.z), Rh[q * 4 + 2], acc2, false);
          acc2 = __builtin_amdgcn_fdot2(__builtin_bit_cast(half2v, v.w), Rh[q * 4 + 3], acc2, false);
        }
        z[b] = acc2;
      }
    }

    // reduce the 4 r-slices within each wave
    #pragma unroll
    for (int b = 0; b < 32; ++b) {
      z[b] += __shfl_xor(z[b], 16);
      z[b] += __shfl_xor(z[b], 32);
    }
    {
      const int w = tid >> 6;
      if ((tid & 48) == 0) {
        #pragma unroll
        for (int b = 0; b < 32; ++b) red[b][w][c] = z[b];
      }
    }
    __syncthreads();

    // cross-wave final sum + xz
    {
      const float za = red[fb0][0][c] + red[fb0][1][c] + red[fb0][2][c] + red[fb0][3][c] + x0;
      const float zb2 = red[fb1][0][c] + red[fb1][1][c] + red[fb1][2][c] + red[fb1][3][c] + x1;
      zbuf[fb0][c] = za;
      zbuf[fb1][c] = zb2;
    }
    __syncthreads();

    if (tid < 128) {
      const float zi = zbuf[b_o][u_o * 4 + 0];
      const float zf = zbuf[b_o][u_o * 4 + 1];
      const float zg = zbuf[b_o][u_o * 4 + 2];
      const float zo = zbuf[b_o][u_o * 4 + 3];
      cst = sigf(zf) * cst + sigf(zi) * tanhf(zg);
      const float h = sigf(zo) * tanhf(cst);
      const float hp2 = __shfl_xor(h, 32);   // partner unit (u_o ^ 1)
      if ((tid & 32) == 0) {                 // u_o even: pack (u, u+1)
        const half2v p = pack2h(h, hp2);
        __hip_atomic_store(&hGd[((size_t)t * BB + b_o) * 256 + blk * 2 + (u_o >> 1)],
                           __builtin_bit_cast(unsigned int, p),
                           __ATOMIC_RELAXED, __HIP_MEMORY_SCOPE_AGENT);
      }
    }
    __syncthreads();   // drains vmcnt => h stores acked at LLC
    if (tid == 0)
      __hip_atomic_store(&flgd[(s * NBLK + blk) * FSTR], 1, __ATOMIC_RELAXED,
                         __HIP_MEMORY_SCOPE_AGENT);
  }
}

// ---------------- dense + SELU (reads packed-f16 h) ----------------
__global__ __launch_bounds__(256) void dense_selu(
    const unsigned int* __restrict__ hGf, const unsigned int* __restrict__ hGb,
    const float* __restrict__ W, const float* __restrict__ bias,
    float* __restrict__ out)
{
  const int bt = blockIdx.x;
  const int b = bt >> 8, t = bt & 255;
  __shared__ float h[1024];
  __shared__ float part[8][33];
  const int tid = threadIdx.x;
  {
    const unsigned int wf = hGf[((size_t)t * BB + b) * 256 + tid];
    const unsigned int wb = hGb[((size_t)t * BB + b) * 256 + tid];
    const half2v f = __builtin_bit_cast(half2v, wf);
    const half2v g = __builtin_bit_cast(half2v, wb);
    h[2 * tid]       = (float)f.x;
    h[2 * tid + 1]   = (float)f.y;
    h[512 + 2 * tid]     = (float)g.x;
    h[512 + 2 * tid + 1] = (float)g.y;
  }
  __syncthreads();
  const int n = tid & 31, s8 = tid >> 5;   // s8: 8 k-slices of 128
  if (n < NTAG) {
    float acc = 0.f;
    const int k0 = s8 * 128;
    #pragma unroll 4
    for (int k = k0; k < k0 + 128; ++k) acc = fmaf(h[k], W[(size_t)k * NTAG + n], acc);
    part[s8][n] = acc;
  }
  __syncthreads();
  if (tid < NTAG) {
    float v = 0.f;
    #pragma unroll
    for (int q = 0; q < 8; ++q) v += part[q][tid];
    v += bias[tid];
    const float scale = 1.0507009873554805f, alf = 1.6732632423543772f;
    v = v > 0.f ? scale * v : scale * alf * (__expf(v) - 1.f);
    out[(size_t)bt * NTAG + tid] = v;
  }
}

// ---------------- CRF NLL ----------------
__global__ __launch_bounds__(64) void crf_kernel(
    const float* __restrict__ logits,
    const int* __restrict__ tags, const int* __restrict__ lens,
    const float* __restrict__ trans, float* __restrict__ nll)
{
  const int b = blockIdx.x;
  const int tid = threadIdx.x;
  __shared__ float tr[NTAG * NTAG];
  __shared__ float al[NTAG];
  __shared__ float red[2];
  for (int i = tid; i < NTAG * NTAG; i += 64) tr[i] = trans[i];
  __syncthreads();

  int len = lens[b];
  len = len < 1 ? 1 : (len > TT ? TT : len);
  const size_t base = (size_t)b * TT;

  float us = 0.f, bs = 0.f;
  for (int t = tid; t < TT; t += 64) {
    if (t < len) us += logits[(base + t) * NTAG + tags[base + t]];
    if (t >= 1 && t < len) bs += tr[tags[base + t - 1] * NTAG + tags[base + t]];
  }
  #pragma unroll
  for (int off = 32; off > 0; off >>= 1) {
    us += __shfl_down(us, off);
    bs += __shfl_down(bs, off);
  }
  if (tid == 0) { red[0] = us; red[1] = bs; }

  if (tid < NTAG) al[tid] = logits[base * NTAG + tid];
  __syncthreads();

  for (int t = 1; t < len; ++t) {
    float nv = 0.f;
    if (tid < NTAG) {
      float m = -3.4e38f;
      #pragma unroll
      for (int i = 0; i < NTAG; ++i) m = fmaxf(m, al[i] + tr[i * NTAG + tid]);
      float ss = 0.f;
      #pragma unroll
      for (int i = 0; i < NTAG; ++i) ss += __expf(al[i] + tr[i * NTAG + tid] - m);
      nv = m + __logf(ss) + logits[(base + t) * NTAG + tid];
    }
    __syncthreads();
    if (tid < NTAG) al[tid] = nv;
    __syncthreads();
  }

  if (tid == 0) {
    float m = -3.4e38f;
    for (int i = 0; i < NTAG; ++i) m = fmaxf(m, al[i]);
    float ss = 0.f;
    for (int i = 0; i < NTAG; ++i) ss += __expf(al[i] - m);
    const float logz = m + __logf(ss);
    nll[b] = -(red[0] + red[1] - logz);
  }
}

__global__ __launch_bounds__(64) void finalize(const float* __restrict__ nll, float* __restrict__ out) {
  float v = (threadIdx.x < BB) ? nll[threadIdx.x] : 0.f;
  #pragma unroll
  for (int off = 32; off > 0; off >>= 1) v += __shfl_down(v, off);
  if (threadIdx.x == 0) out[0] = v * (1.f / BB);
}

extern "C" void kernel_launch(void* const* d_in, const int* in_sizes, int n_in,
                              void* d_out, int out_size, void* d_ws, size_t ws_size,
                              hipStream_t stream) {
  const float* emb  = (const float*)d_in[0];
  const int* tags   = (const int*)d_in[1];
  const int* lens   = (const int*)d_in[2];
  const float* kf   = (const float*)d_in[3];
  const float* rf   = (const float*)d_in[4];
  const float* bf   = (const float*)d_in[5];
  const float* kb   = (const float*)d_in[6];
  const float* rb   = (const float*)d_in[7];
  const float* bb   = (const float*)d_in[8];
  const float* dw   = (const float*)d_in[9];
  const float* db   = (const float*)d_in[10];
  const float* trans= (const float*)d_in[11];
  float* out = (float*)d_out;

  float* ws  = (float*)d_ws;
  float* xzf = ws;
  float* xzb = xzf + (size_t)BT * GATES;
  unsigned int* hGf = (unsigned int*)(xzb + (size_t)BT * GATES);  // TT*BB*256 dwords = 8 MB
  unsigned int* hGb = hGf + (size_t)TT * BB * 256;
  float* nll = (float*)(hGb + (size_t)TT * BB * 256);
  int*   flg = (int*)(nll + 64);               // 2*256*128*4 = 262144 ints
  int*   ep  = flg + 2 * TT * NBLK * FSTR;     // 2*256*8*16  = 65536 ints

  // zero the step flags + epochs (required every call; graph-safe)
  (void)hipMemsetAsync(flg, 0,
                       (size_t)(2 * TT * NBLK * FSTR + 2 * TT * EREP * ESTR) * 4,
                       stream);

  gemm_xz<<<dim3(32, 64), 256, 0, stream>>>(emb, kf, kb, bf, bb, xzf, xzb);
  lstm_persist<<<2 * NBLK, 256, 0, stream>>>(xzf, xzb, rf, rb, hGf, hGb, flg, ep);
  dense_selu<<<8192, 256, 0, stream>>>(hGf, hGb, dw, db, out + 1);
  crf_kernel<<<32, 64, 0, stream>>>(out + 1, tags, lens, trans, nll);
  finalize<<<1, 64, 0, stream>>>(nll, out);
}

// Round 9
// 1753.736 us; speedup vs baseline: 5.9013x; 1.2652x over previous
//
#include <hip/hip_runtime.h>
#include <hip/hip_bf16.h>
#include <math.h>

#define HID 512
#define GATES 2048
#define BT 8192   // 32*256
#define TT 256
#define BB 32
#define DIN 768
#define NTAG 25
#define UPB 4     // hidden units per persistent block
#define NBLK 128  // blocks per direction
#define FSTR 4    // flag stride in ints (16 B)
#define EREP 8    // epoch flag replicas
#define ESTR 16   // epoch replica stride in ints (64 B)

typedef _Float16 half2v __attribute__((ext_vector_type(2)));
typedef _Float16 half8  __attribute__((ext_vector_type(8)));
typedef float    f32x4  __attribute__((ext_vector_type(4)));

__device__ __forceinline__ half2v pack2h(float a, float b) {
  return __builtin_bit_cast(half2v, __builtin_amdgcn_cvt_pkrtz(a, b));
}

__device__ __forceinline__ float sigf(float x) { return 1.f / (1.f + __expf(-x)); }

// ---------------- prep: KT[n][k] = (f16)K[k][n] ----------------
// 64x64 tiles through LDS; coalesced fp32 reads, coalesced 16B f16 writes.
__global__ __launch_bounds__(256) void transpose_k(
    const float* __restrict__ Kf, const float* __restrict__ Kb,
    unsigned short* __restrict__ KTf, unsigned short* __restrict__ KTb)
{
  const int dir = blockIdx.z;
  const float* __restrict__ K = dir ? Kb : Kf;
  unsigned short* __restrict__ KT = dir ? KTb : KTf;
  const int k0 = blockIdx.x * 64;
  const int n0 = blockIdx.y * 64;
  __shared__ float tile[64][65];
  const int tid = threadIdx.x;
  #pragma unroll
  for (int p = 0; p < 4; ++p) {
    const int idx = p * 256 + tid;
    const int kr = idx >> 4, c4 = (idx & 15) * 4;
    const float4 v = *(const float4*)(K + (size_t)(k0 + kr) * GATES + n0 + c4);
    tile[kr][c4 + 0] = v.x; tile[kr][c4 + 1] = v.y;
    tile[kr][c4 + 2] = v.z; tile[kr][c4 + 3] = v.w;
  }
  __syncthreads();
  #pragma unroll
  for (int p = 0; p < 2; ++p) {
    const int idx = p * 256 + tid;
    const int nr = idx >> 3, s = (idx & 7) * 8;
    half8 hv;
    #pragma unroll
    for (int x = 0; x < 8; ++x) hv[x] = (_Float16)tile[s + x][nr];
    *(half8*)(KT + (size_t)(n0 + nr) * DIN + k0 + s) = hv;
  }
}

// ---------------- GEMM (f16 MFMA): xz = emb @ K(dir) + bias(dir) ----------
// 128x128 tile, BK=64, 4 waves (2x2), mfma_f32_16x16x32_f16.
// LDS tiles XOR-swizzled (slot ^= row&7) so fragment ds_read_b128 is
// conflict-free. A and B use the SAME per-lane k placement, so the result is
// exact regardless of the hardware's internal k ordering.
__global__ __launch_bounds__(256) void gemm_xz(
    const float* __restrict__ emb,
    const unsigned short* __restrict__ KTf, const unsigned short* __restrict__ KTb,
    const float* __restrict__ bf, const float* __restrict__ bb,
    float* __restrict__ xzf, float* __restrict__ xzb)
{
  const int dir = blockIdx.z;
  const unsigned short* __restrict__ KT = dir ? KTb : KTf;
  const float* __restrict__ bias = dir ? bb : bf;
  float* __restrict__ C = dir ? xzb : xzf;
  const int n0 = blockIdx.x * 128;
  const int m0 = blockIdx.y * 128;

  __shared__ __align__(16) char A_lds[128 * 64 * 2];  // 16 KB f16 [m][k]
  __shared__ __align__(16) char B_lds[128 * 64 * 2];  // 16 KB f16 [n][k]

  const int tid = threadIdx.x;
  const int lane = tid & 63, wid = tid >> 6;
  const int wm = wid >> 1, wn = wid & 1;
  const int lm = lane & 15, lk = lane >> 4;   // frag row/col and k-group

  f32x4 acc[4][4];
  #pragma unroll
  for (int i = 0; i < 4; ++i)
    #pragma unroll
    for (int j = 0; j < 4; ++j) acc[i][j] = (f32x4){0.f, 0.f, 0.f, 0.f};

  for (int kt = 0; kt < DIN / 64; ++kt) {
    const int k0 = kt * 64;
    __syncthreads();
    // stage A: emb fp32 -> f16, swizzled ds_write_b128
    #pragma unroll
    for (int p = 0; p < 4; ++p) {
      const int id = p * 256 + tid;
      const int r = id >> 3, s = id & 7;
      const float* src = emb + (size_t)(m0 + r) * DIN + k0 + s * 8;
      const float4 v0 = *(const float4*)(src);
      const float4 v1 = *(const float4*)(src + 4);
      half8 hv;
      hv[0] = (_Float16)v0.x; hv[1] = (_Float16)v0.y;
      hv[2] = (_Float16)v0.z; hv[3] = (_Float16)v0.w;
      hv[4] = (_Float16)v1.x; hv[5] = (_Float16)v1.y;
      hv[6] = (_Float16)v1.z; hv[7] = (_Float16)v1.w;
      *(half8*)(A_lds + r * 128 + ((s ^ (r & 7)) << 4)) = hv;
    }
    // stage B: KT f16 raw copy, swizzled
    #pragma unroll
    for (int p = 0; p < 4; ++p) {
      const int id = p * 256 + tid;
      const int r = id >> 3, s = id & 7;
      const uint4 v = *(const uint4*)(KT + (size_t)(n0 + r) * DIN + k0 + s * 8);
      *(uint4*)(B_lds + r * 128 + ((s ^ (r & 7)) << 4)) = v;
    }
    __syncthreads();

    #pragma unroll
    for (int kh = 0; kh < 2; ++kh) {
      half8 a[4], b[4];
      #pragma unroll
      for (int mt = 0; mt < 4; ++mt) {
        const int rloc = wm * 64 + mt * 16 + lm;
        const int kslot = kh * 4 + lk;
        a[mt] = *(const half8*)(A_lds + rloc * 128 + ((kslot ^ (rloc & 7)) << 4));
      }
      #pragma unroll
      for (int nt = 0; nt < 4; ++nt) {
        const int nloc = wn * 64 + nt * 16 + lm;
        const int kslot = kh * 4 + lk;
        b[nt] = *(const half8*)(B_lds + nloc * 128 + ((kslot ^ (nloc & 7)) << 4));
      }
      #pragma unroll
      for (int mt = 0; mt < 4; ++mt)
        #pragma unroll
        for (int nt = 0; nt < 4; ++nt)
          acc[mt][nt] = __builtin_amdgcn_mfma_f32_16x16x32_f16(a[mt], b[nt], acc[mt][nt], 0, 0, 0);
    }
  }

  // epilogue: C[m][n] = acc + bias[n]; C/D layout col=lane&15, row=(lane>>4)*4+reg
  #pragma unroll
  for (int nt = 0; nt < 4; ++nt) {
    const int col = n0 + wn * 64 + nt * 16 + lm;
    const float bs = bias[col];
    #pragma unroll
    for (int mt = 0; mt < 4; ++mt) {
      const int rowb = m0 + wm * 64 + mt * 16 + lk * 4;
      const f32x4 v = acc[mt][nt];
      #pragma unroll
      for (int g = 0; g < 4; ++g)
        C[(size_t)(rowb + g) * GATES + col] = v[g] + bs;
    }
  }
}

// ---------------- Persistent BiLSTM (fence-free, f16 data path) ----------
__global__ __launch_bounds__(256, 1) void lstm_persist(
    const float* __restrict__ xzf, const float* __restrict__ xzb,
    const float* __restrict__ Rf, const float* __restrict__ Rb,
    unsigned int* __restrict__ hGf, unsigned int* __restrict__ hGb,
    int* __restrict__ flg,    // [2 dir][256 step][NBLK * FSTR]
    int* __restrict__ ep)     // [2 dir][256 step][EREP * ESTR]
{
  const int bid = blockIdx.x;
  const int dir = bid & 1;
  const int blk = bid >> 1;            // 0..127
  const int u0 = blk * UPB;
  const int tid = threadIdx.x;
  const int c = tid & 15;
  const int r = tid >> 4;              // 0..15: k-slice [r*32, r*32+32)
  const int gt = c & 3, uu = c >> 2;
  const int j = gt * HID + u0 + uu;    // gate-major column

  const float* __restrict__ R  = dir ? Rb : Rf;
  const float* __restrict__ xz = dir ? xzb : xzf;
  unsigned int* __restrict__ hGd = dir ? hGb : hGf;
  int* __restrict__ flgd = flg + (size_t)dir * TT * NBLK * FSTR;
  int* __restrict__ epd  = ep  + (size_t)dir * TT * EREP * ESTR;

  // h tile: 32 b x 16 chunks x 20 dwords (16 data + 4 pad) = 40 KB
  __shared__ unsigned int hsw[BB * 320];
  __shared__ float red[BB][4][17];
  __shared__ float zbuf[BB][20];

  // R slice as f16 pairs: Rh[m] = (R[r*32+2m][j], R[r*32+2m+1][j])
  half2v Rh[16];
  #pragma unroll
  for (int m = 0; m < 16; ++m) {
    const int k = r * 32 + 2 * m;
    const float f0 = R[(size_t)k * GATES + j];
    const float f1 = R[(size_t)(k + 1) * GATES + j];
    Rh[m] = pack2h(f0, f1);
  }

  float cst = 0.f;                     // cell state (tid<128)
  const int b_o = tid & 31, u_o = tid >> 5;
  uint4* hs4 = (uint4*)hsw;
  const int fb0 = r, fb1 = r + 16;
  const bool leader = (blk == 0);

  for (int s = 0; s < TT; ++s) {
    const int t = dir ? (TT - 1 - s) : s;

    // prefetch xz for the finalize phase (overlaps the poll)
    const float x0 = xz[((size_t)fb0 * TT + t) * GATES + j];
    const float x1 = xz[((size_t)fb1 * TT + t) * GATES + j];

    if (s > 0) {
      const int tprev = dir ? t + 1 : t - 1;
      if (leader) {
        if (tid < NBLK) {
          while (!__hip_atomic_load(&flgd[((s - 1) * NBLK + tid) * FSTR],
                                    __ATOMIC_RELAXED, __HIP_MEMORY_SCOPE_AGENT))
            __builtin_amdgcn_s_sleep(1);
        }
        __syncthreads();
        if (tid < EREP)   // publish BEFORE staging so followers unblock now
          __hip_atomic_store(&epd[((s - 1) * EREP + tid) * ESTR], 1,
                             __ATOMIC_RELAXED, __HIP_MEMORY_SCOPE_AGENT);
      } else {
        if (tid == 0) {
          while (!__hip_atomic_load(&epd[((s - 1) * EREP + (blk & 7)) * ESTR],
                                    __ATOMIC_RELAXED, __HIP_MEMORY_SCOPE_AGENT))
            __builtin_amdgcn_s_sleep(1);
        }
        __syncthreads();
      }
      // stage packed-f16 h(s-1) -> LDS (2048 uint4 total, 8 per thread)
      const uint4* hsrc = (const uint4*)(hGd + (size_t)tprev * BB * 256);
      #pragma unroll
      for (int it = 0; it < 8; ++it) {
        const int g4 = tid + it * 256;
        const uint4 v = hsrc[g4];
        const int b = g4 >> 6, rem = g4 & 63;
        hs4[b * 80 + (rem >> 2) * 5 + (rem & 3)] = v;
      }
    } else {
      const uint4 zz = make_uint4(0u, 0u, 0u, 0u);
      #pragma unroll
      for (int it = 0; it < 10; ++it)
        hs4[tid + it * 256] = zz;
    }
    __syncthreads();

    // z-loop: 32 batch accumulators; 4 ds_read_b128 + 16 fdot2 per batch
    float z[32];
    {
      const uint4* hp0 = hs4 + r * 5;
      #pragma unroll
      for (int b = 0; b < 32; ++b) {
        const uint4* hp = hp0 + b * 80;
        float acc2 = 0.f;
        #pragma unroll
        for (int q = 0; q < 4; ++q) {
          const uint4 v = hp[q];
          acc2 = __builtin_amdgcn_fdot2(__builtin_bit_cast(half2v, v.x), Rh[q * 4 + 0], acc2, false);
          acc2 = __builtin_amdgcn_fdot2(__builtin_bit_cast(half2v, v.y), Rh[q * 4 + 1], acc2, false);
          acc2 = __builtin_amdgcn_fdot2(__builtin_bit_cast(half2v, v.z), Rh[q * 4 + 2], acc2, false);
          acc2 = __builtin_amdgcn_fdot2(__builtin_bit_cast(half2v, v.w), Rh[q * 4 + 3], acc2, false);
        }
        z[b] = acc2;
      }
    }

    // reduce the 4 r-slices within each wave
    #pragma unroll
    for (int b = 0; b < 32; ++b) {
      z[b] += __shfl_xor(z[b], 16);
      z[b] += __shfl_xor(z[b], 32);
    }
    {
      const int w = tid >> 6;
      if ((tid & 48) == 0) {
        #pragma unroll
        for (int b = 0; b < 32; ++b) red[b][w][c] = z[b];
      }
    }
    __syncthreads();

    // cross-wave final sum + xz
    {
      const float za = red[fb0][0][c] + red[fb0][1][c] + red[fb0][2][c] + red[fb0][3][c] + x0;
      const float zb2 = red[fb1][0][c] + red[fb1][1][c] + red[fb1][2][c] + red[fb1][3][c] + x1;
      zbuf[fb0][c] = za;
      zbuf[fb1][c] = zb2;
    }
    __syncthreads();

    if (tid < 128) {
      const float zi = zbuf[b_o][u_o * 4 + 0];
      const float zf = zbuf[b_o][u_o * 4 + 1];
      const float zg = zbuf[b_o][u_o * 4 + 2];
      const float zo = zbuf[b_o][u_o * 4 + 3];
      cst = sigf(zf) * cst + sigf(zi) * tanhf(zg);
      const float h = sigf(zo) * tanhf(cst);
      const float hp2 = __shfl_xor(h, 32);   // partner unit (u_o ^ 1)
      if ((tid & 32) == 0) {                 // u_o even: pack (u, u+1)
        const half2v p = pack2h(h, hp2);
        __hip_atomic_store(&hGd[((size_t)t * BB + b_o) * 256 + blk * 2 + (u_o >> 1)],
                           __builtin_bit_cast(unsigned int, p),
                           __ATOMIC_RELAXED, __HIP_MEMORY_SCOPE_AGENT);
      }
    }
    __syncthreads();   // drains vmcnt => h stores acked at LLC
    if (tid == 0)
      __hip_atomic_store(&flgd[(s * NBLK + blk) * FSTR], 1, __ATOMIC_RELAXED,
                         __HIP_MEMORY_SCOPE_AGENT);
  }
}

// ---------------- dense + SELU (reads packed-f16 h) ----------------
__global__ __launch_bounds__(256) void dense_selu(
    const unsigned int* __restrict__ hGf, const unsigned int* __restrict__ hGb,
    const float* __restrict__ W, const float* __restrict__ bias,
    float* __restrict__ out)
{
  const int bt = blockIdx.x;
  const int b = bt >> 8, t = bt & 255;
  __shared__ float h[1024];
  __shared__ float part[8][33];
  const int tid = threadIdx.x;
  {
    const unsigned int wf = hGf[((size_t)t * BB + b) * 256 + tid];
    const unsigned int wb = hGb[((size_t)t * BB + b) * 256 + tid];
    const half2v f = __builtin_bit_cast(half2v, wf);
    const half2v g = __builtin_bit_cast(half2v, wb);
    h[2 * tid]       = (float)f.x;
    h[2 * tid + 1]   = (float)f.y;
    h[512 + 2 * tid]     = (float)g.x;
    h[512 + 2 * tid + 1] = (float)g.y;
  }
  __syncthreads();
  const int n = tid & 31, s8 = tid >> 5;   // s8: 8 k-slices of 128
  if (n < NTAG) {
    float acc = 0.f;
    const int k0 = s8 * 128;
    #pragma unroll 4
    for (int k = k0; k < k0 + 128; ++k) acc = fmaf(h[k], W[(size_t)k * NTAG + n], acc);
    part[s8][n] = acc;
  }
  __syncthreads();
  if (tid < NTAG) {
    float v = 0.f;
    #pragma unroll
    for (int q = 0; q < 8; ++q) v += part[q][tid];
    v += bias[tid];
    const float scale = 1.0507009873554805f, alf = 1.6732632423543772f;
    v = v > 0.f ? scale * v : scale * alf * (__expf(v) - 1.f);
    out[(size_t)bt * NTAG + tid] = v;
  }
}

// ---------------- CRF NLL ----------------
__global__ __launch_bounds__(64) void crf_kernel(
    const float* __restrict__ logits,
    const int* __restrict__ tags, const int* __restrict__ lens,
    const float* __restrict__ trans, float* __restrict__ nll)
{
  const int b = blockIdx.x;
  const int tid = threadIdx.x;
  __shared__ float tr[NTAG * NTAG];
  __shared__ float al[NTAG];
  __shared__ float red[2];
  for (int i = tid; i < NTAG * NTAG; i += 64) tr[i] = trans[i];
  __syncthreads();

  int len = lens[b];
  len = len < 1 ? 1 : (len > TT ? TT : len);
  const size_t base = (size_t)b * TT;

  float us = 0.f, bs = 0.f;
  for (int t = tid; t < TT; t += 64) {
    if (t < len) us += logits[(base + t) * NTAG + tags[base + t]];
    if (t >= 1 && t < len) bs += tr[tags[base + t - 1] * NTAG + tags[base + t]];
  }
  #pragma unroll
  for (int off = 32; off > 0; off >>= 1) {
    us += __shfl_down(us, off);
    bs += __shfl_down(bs, off);
  }
  if (tid == 0) { red[0] = us; red[1] = bs; }

  if (tid < NTAG) al[tid] = logits[base * NTAG + tid];
  __syncthreads();

  for (int t = 1; t < len; ++t) {
    float nv = 0.f;
    if (tid < NTAG) {
      float m = -3.4e38f;
      #pragma unroll
      for (int i = 0; i < NTAG; ++i) m = fmaxf(m, al[i] + tr[i * NTAG + tid]);
      float ss = 0.f;
      #pragma unroll
      for (int i = 0; i < NTAG; ++i) ss += __expf(al[i] + tr[i * NTAG + tid] - m);
      nv = m + __logf(ss) + logits[(base + t) * NTAG + tid];
    }
    __syncthreads();
    if (tid < NTAG) al[tid] = nv;
    __syncthreads();
  }

  if (tid == 0) {
    float m = -3.4e38f;
    for (int i = 0; i < NTAG; ++i) m = fmaxf(m, al[i]);
    float ss = 0.f;
    for (int i = 0; i < NTAG; ++i) ss += __expf(al[i] - m);
    const float logz = m + __logf(ss);
    nll[b] = -(red[0] + red[1] - logz);
  }
}

__global__ __launch_bounds__(64) void finalize(const float* __restrict__ nll, float* __restrict__ out) {
  float v = (threadIdx.x < BB) ? nll[threadIdx.x] : 0.f;
  #pragma unroll
  for (int off = 32; off > 0; off >>= 1) v += __shfl_down(v, off);
  if (threadIdx.x == 0) out[0] = v * (1.f / BB);
}

extern "C" void kernel_launch(void* const* d_in, const int* in_sizes, int n_in,
                              void* d_out, int out_size, void* d_ws, size_t ws_size,
                              hipStream_t stream) {
  const float* emb  = (const float*)d_in[0];
  const int* tags   = (const int*)d_in[1];
  const int* lens   = (const int*)d_in[2];
  const float* kf   = (const float*)d_in[3];
  const float* rf   = (const float*)d_in[4];
  const float* bf   = (const float*)d_in[5];
  const float* kb   = (const float*)d_in[6];
  const float* rb   = (const float*)d_in[7];
  const float* bb   = (const float*)d_in[8];
  const float* dw   = (const float*)d_in[9];
  const float* db   = (const float*)d_in[10];
  const float* trans= (const float*)d_in[11];
  float* out = (float*)d_out;

  float* ws  = (float*)d_ws;
  float* xzf = ws;
  float* xzb = xzf + (size_t)BT * GATES;
  unsigned int* hGf = (unsigned int*)(xzb + (size_t)BT * GATES);  // TT*BB*256 dwords = 8 MB
  unsigned int* hGb = hGf + (size_t)TT * BB * 256;
  unsigned short* KTf = (unsigned short*)(hGb + (size_t)TT * BB * 256);  // 2048*768 f16
  unsigned short* KTb = KTf + (size_t)GATES * DIN;
  float* nll = (float*)(KTb + (size_t)GATES * DIN);
  int*   flg = (int*)(nll + 64);               // 2*256*128*4 = 262144 ints
  int*   ep  = flg + 2 * TT * NBLK * FSTR;     // 2*256*8*16  = 65536 ints

  // zero the step flags + epochs (required every call; graph-safe)
  (void)hipMemsetAsync(flg, 0,
                       (size_t)(2 * TT * NBLK * FSTR + 2 * TT * EREP * ESTR) * 4,
                       stream);

  transpose_k<<<dim3(DIN / 64, GATES / 64, 2), 256, 0, stream>>>(kf, kb, KTf, KTb);
  gemm_xz<<<dim3(GATES / 128, BT / 128, 2), 256, 0, stream>>>(emb, KTf, KTb, bf, bb, xzf, xzb);
  lstm_persist<<<2 * NBLK, 256, 0, stream>>>(xzf, xzb, rf, rb, hGf, hGb, flg, ep);
  dense_selu<<<8192, 256, 0, stream>>>(hGf, hGb, dw, db, out + 1);
  crf_kernel<<<32, 64, 0, stream>>>(out + 1, tags, lens, trans, nll);
  finalize<<<1, 64, 0, stream>>>(nll, out);
}

// Round 10
// 982.084 us; speedup vs baseline: 10.5381x; 1.7857x over previous
//
#include <hip/hip_runtime.h>
#include <hip/hip_bf16.h>
#include <math.h>

#define HID 512
#define GATES 2048
#define BT 8192   // 32*256
#define TT 256
#define BB 32
#define DIN 768
#define NTAG 25
#define UPB 4     // hidden units per persistent block
#define NBLK 128  // blocks per direction
#define FSTR 4    // flag stride in ints (16 B)
#define EREP 8    // epoch flag replicas
#define ESTR 16   // epoch replica stride in ints (64 B)

typedef _Float16 half2v __attribute__((ext_vector_type(2)));
typedef _Float16 half8  __attribute__((ext_vector_type(8)));
typedef float    f32x4  __attribute__((ext_vector_type(4)));

__device__ __forceinline__ half2v pack2h(float a, float b) {
  return __builtin_bit_cast(half2v, __builtin_amdgcn_cvt_pkrtz(a, b));
}

__device__ __forceinline__ float sigf(float x) { return 1.f / (1.f + __expf(-x)); }

// ---------------- prep: KT[n][k] = (f16)K[k][n] ----------------
__global__ __launch_bounds__(256) void transpose_k(
    const float* __restrict__ Kf, const float* __restrict__ Kb,
    unsigned short* __restrict__ KTf, unsigned short* __restrict__ KTb)
{
  const int dir = blockIdx.z;
  const float* __restrict__ K = dir ? Kb : Kf;
  unsigned short* __restrict__ KT = dir ? KTb : KTf;
  const int k0 = blockIdx.x * 64;
  const int n0 = blockIdx.y * 64;
  __shared__ float tile[64][65];
  const int tid = threadIdx.x;
  #pragma unroll
  for (int p = 0; p < 4; ++p) {
    const int idx = p * 256 + tid;
    const int kr = idx >> 4, c4 = (idx & 15) * 4;
    const float4 v = *(const float4*)(K + (size_t)(k0 + kr) * GATES + n0 + c4);
    tile[kr][c4 + 0] = v.x; tile[kr][c4 + 1] = v.y;
    tile[kr][c4 + 2] = v.z; tile[kr][c4 + 3] = v.w;
  }
  __syncthreads();
  #pragma unroll
  for (int p = 0; p < 2; ++p) {
    const int idx = p * 256 + tid;
    const int nr = idx >> 3, s = (idx & 7) * 8;
    half8 hv;
    #pragma unroll
    for (int x = 0; x < 8; ++x) hv[x] = (_Float16)tile[s + x][nr];
    *(half8*)(KT + (size_t)(n0 + nr) * DIN + k0 + s) = hv;
  }
}

// ---------------- GEMM (f16 MFMA): xz = emb @ K(dir) + bias(dir) ----------
__global__ __launch_bounds__(256) void gemm_xz(
    const float* __restrict__ emb,
    const unsigned short* __restrict__ KTf, const unsigned short* __restrict__ KTb,
    const float* __restrict__ bf, const float* __restrict__ bb,
    float* __restrict__ xzf, float* __restrict__ xzb)
{
  const int dir = blockIdx.z;
  const unsigned short* __restrict__ KT = dir ? KTb : KTf;
  const float* __restrict__ bias = dir ? bb : bf;
  float* __restrict__ C = dir ? xzb : xzf;
  const int n0 = blockIdx.x * 128;
  const int m0 = blockIdx.y * 128;

  __shared__ __align__(16) char A_lds[128 * 64 * 2];  // 16 KB f16 [m][k]
  __shared__ __align__(16) char B_lds[128 * 64 * 2];  // 16 KB f16 [n][k]

  const int tid = threadIdx.x;
  const int lane = tid & 63, wid = tid >> 6;
  const int wm = wid >> 1, wn = wid & 1;
  const int lm = lane & 15, lk = lane >> 4;   // frag row/col and k-group

  f32x4 acc[4][4];
  #pragma unroll
  for (int i = 0; i < 4; ++i)
    #pragma unroll
    for (int j = 0; j < 4; ++j) acc[i][j] = (f32x4){0.f, 0.f, 0.f, 0.f};

  for (int kt = 0; kt < DIN / 64; ++kt) {
    const int k0 = kt * 64;
    __syncthreads();
    #pragma unroll
    for (int p = 0; p < 4; ++p) {
      const int id = p * 256 + tid;
      const int r = id >> 3, s = id & 7;
      const float* src = emb + (size_t)(m0 + r) * DIN + k0 + s * 8;
      const float4 v0 = *(const float4*)(src);
      const float4 v1 = *(const float4*)(src + 4);
      half8 hv;
      hv[0] = (_Float16)v0.x; hv[1] = (_Float16)v0.y;
      hv[2] = (_Float16)v0.z; hv[3] = (_Float16)v0.w;
      hv[4] = (_Float16)v1.x; hv[5] = (_Float16)v1.y;
      hv[6] = (_Float16)v1.z; hv[7] = (_Float16)v1.w;
      *(half8*)(A_lds + r * 128 + ((s ^ (r & 7)) << 4)) = hv;
    }
    #pragma unroll
    for (int p = 0; p < 4; ++p) {
      const int id = p * 256 + tid;
      const int r = id >> 3, s = id & 7;
      const uint4 v = *(const uint4*)(KT + (size_t)(n0 + r) * DIN + k0 + s * 8);
      *(uint4*)(B_lds + r * 128 + ((s ^ (r & 7)) << 4)) = v;
    }
    __syncthreads();

    #pragma unroll
    for (int kh = 0; kh < 2; ++kh) {
      half8 a[4], b[4];
      #pragma unroll
      for (int mt = 0; mt < 4; ++mt) {
        const int rloc = wm * 64 + mt * 16 + lm;
        const int kslot = kh * 4 + lk;
        a[mt] = *(const half8*)(A_lds + rloc * 128 + ((kslot ^ (rloc & 7)) << 4));
      }
      #pragma unroll
      for (int nt = 0; nt < 4; ++nt) {
        const int nloc = wn * 64 + nt * 16 + lm;
        const int kslot = kh * 4 + lk;
        b[nt] = *(const half8*)(B_lds + nloc * 128 + ((kslot ^ (nloc & 7)) << 4));
      }
      #pragma unroll
      for (int mt = 0; mt < 4; ++mt)
        #pragma unroll
        for (int nt = 0; nt < 4; ++nt)
          acc[mt][nt] = __builtin_amdgcn_mfma_f32_16x16x32_f16(a[mt], b[nt], acc[mt][nt], 0, 0, 0);
    }
  }

  #pragma unroll
  for (int nt = 0; nt < 4; ++nt) {
    const int col = n0 + wn * 64 + nt * 16 + lm;
    const float bs = bias[col];
    #pragma unroll
    for (int mt = 0; mt < 4; ++mt) {
      const int rowb = m0 + wm * 64 + mt * 16 + lk * 4;
      const f32x4 v = acc[mt][nt];
      #pragma unroll
      for (int g = 0; g < 4; ++g)
        C[(size_t)(rowb + g) * GATES + col] = v[g] + bs;
    }
  }
}

// ---------------- Persistent BiLSTM (fence-free, MFMA z-loop) ----------
// 256 blocks x 256 threads; dir = bid&1, blk = bid>>1 owns 4 hidden units x 4
// gates (16 cols) for all 32 batches. Per step the z-matmul
// [32 b x 512 k] @ [512 k x 16 cols] runs on MFMA 16x16x32_f16: 16 k-tiles
// split over 4 waves (8 MFMA/wave, R B-frags preloaded in regs), partials
// reduced across waves via LDS. h-tile LDS: uint4 row stride 65 (odd mod 8 =>
// conflict-free staging writes, ~2-way frag reads = free). h exchanged as
// packed f16 through hG (write-once, agent-scope stores, cached first-touch
// reads => fence-free). Sync: producer flags + leader-published epoch lines.
__global__ __launch_bounds__(256, 1) void lstm_persist(
    const float* __restrict__ xzf, const float* __restrict__ xzb,
    const float* __restrict__ Rf, const float* __restrict__ Rb,
    unsigned int* __restrict__ hGf, unsigned int* __restrict__ hGb,
    int* __restrict__ flg,    // [2 dir][256 step][NBLK * FSTR]
    int* __restrict__ ep)     // [2 dir][256 step][EREP * ESTR]
{
  const int bid = blockIdx.x;
  const int dir = bid & 1;
  const int blk = bid >> 1;            // 0..127
  const int u0 = blk * UPB;
  const int tid = threadIdx.x;
  const int c = tid & 15;              // col 0..15 (gt = c&3, uu = c>>2)
  const int j = (c & 3) * HID + u0 + (c >> 2);   // gate-major column
  const int lane = tid & 63, w = tid >> 6;       // wave id 0..3
  const int lm = lane & 15, lk = lane >> 4;      // frag indices

  const float* __restrict__ R  = dir ? Rb : Rf;
  const float* __restrict__ xz = dir ? xzb : xzf;
  unsigned int* __restrict__ hGd = dir ? hGb : hGf;
  int* __restrict__ flgd = flg + (size_t)dir * TT * NBLK * FSTR;
  int* __restrict__ epd  = ep  + (size_t)dir * TT * EREP * ESTR;

  __shared__ uint4 hs4[BB * 65];       // h tile [b][k4] stride 65, 33.3 KB
  __shared__ float redm[4][BB][18];    // per-wave C partials, 9.2 KB
  __shared__ float zbuf[BB][20];       // final gate pre-activations

  // B-frags: wave w covers k-tiles w*4+kti; lane holds R[kb..kb+7][j]
  half8 Rbf[4];
  #pragma unroll
  for (int kti = 0; kti < 4; ++kti) {
    const int kb = (w * 4 + kti) * 32 + lk * 8;
    half8 hv;
    #pragma unroll
    for (int x = 0; x < 8; ++x) hv[x] = (_Float16)R[(size_t)(kb + x) * GATES + j];
    Rbf[kti] = hv;
  }

  float cst = 0.f;                     // cell state (tid<128)
  const int b_o = tid & 31, u_o = tid >> 5;
  const int fb0 = tid >> 4, fb1 = (tid >> 4) + 16;
  const bool leader = (blk == 0);

  for (int s = 0; s < TT; ++s) {
    const int t = dir ? (TT - 1 - s) : s;

    // prefetch xz for the finalize phase (overlaps the poll)
    const float x0 = xz[((size_t)fb0 * TT + t) * GATES + j];
    const float x1 = xz[((size_t)fb1 * TT + t) * GATES + j];

    if (s > 0) {
      const int tprev = dir ? t + 1 : t - 1;
      if (leader) {
        if (tid < NBLK) {
          while (!__hip_atomic_load(&flgd[((s - 1) * NBLK + tid) * FSTR],
                                    __ATOMIC_RELAXED, __HIP_MEMORY_SCOPE_AGENT))
            __builtin_amdgcn_s_sleep(1);
        }
        __syncthreads();
        if (tid < EREP)   // publish BEFORE staging so followers unblock now
          __hip_atomic_store(&epd[((s - 1) * EREP + tid) * ESTR], 1,
                             __ATOMIC_RELAXED, __HIP_MEMORY_SCOPE_AGENT);
      } else {
        if (tid == 0) {
          while (!__hip_atomic_load(&epd[((s - 1) * EREP + (blk & 7)) * ESTR],
                                    __ATOMIC_RELAXED, __HIP_MEMORY_SCOPE_AGENT))
            __builtin_amdgcn_s_sleep(1);
        }
        __syncthreads();
      }
      // stage packed-f16 h(s-1) -> LDS (2048 uint4, 8 per thread)
      const uint4* hsrc = (const uint4*)(hGd + (size_t)tprev * BB * 256);
      #pragma unroll
      for (int it = 0; it < 8; ++it) {
        const int g4 = tid + it * 256;
        const uint4 v = hsrc[g4];
        hs4[(g4 >> 6) * 65 + (g4 & 63)] = v;
      }
    } else {
      const uint4 zz = make_uint4(0u, 0u, 0u, 0u);
      #pragma unroll
      for (int it = 0; it < 9; ++it) {
        const int idx = tid + it * 256;
        if (idx < BB * 65) hs4[idx] = zz;
      }
    }
    __syncthreads();

    // MFMA z-loop: wave w accumulates its 4 k-tiles for both 16-batch halves
    f32x4 acc0 = (f32x4){0.f, 0.f, 0.f, 0.f};
    f32x4 acc1 = (f32x4){0.f, 0.f, 0.f, 0.f};
    #pragma unroll
    for (int kti = 0; kti < 4; ++kti) {
      const int k4 = (w * 4 + kti) * 4 + lk;
      const half8 a0 = *(const half8*)&hs4[(lm) * 65 + k4];
      const half8 a1 = *(const half8*)&hs4[(16 + lm) * 65 + k4];
      acc0 = __builtin_amdgcn_mfma_f32_16x16x32_f16(a0, Rbf[kti], acc0, 0, 0, 0);
      acc1 = __builtin_amdgcn_mfma_f32_16x16x32_f16(a1, Rbf[kti], acc1, 0, 0, 0);
    }
    // write per-wave partials: D row b = mt*16 + lk*4 + g, col c = lm
    #pragma unroll
    for (int g = 0; g < 4; ++g) {
      redm[w][lk * 4 + g][lm] = acc0[g];
      redm[w][16 + lk * 4 + g][lm] = acc1[g];
    }
    __syncthreads();

    // cross-wave final sum + xz
    {
      const float za = redm[0][fb0][c] + redm[1][fb0][c] + redm[2][fb0][c] + redm[3][fb0][c] + x0;
      const float zb2 = redm[0][fb1][c] + redm[1][fb1][c] + redm[2][fb1][c] + redm[3][fb1][c] + x1;
      zbuf[fb0][c] = za;
      zbuf[fb1][c] = zb2;
    }
    __syncthreads();

    if (tid < 128) {
      const float zi = zbuf[b_o][u_o * 4 + 0];
      const float zf = zbuf[b_o][u_o * 4 + 1];
      const float zg = zbuf[b_o][u_o * 4 + 2];
      const float zo = zbuf[b_o][u_o * 4 + 3];
      cst = sigf(zf) * cst + sigf(zi) * tanhf(zg);
      const float h = sigf(zo) * tanhf(cst);
      const float hp2 = __shfl_xor(h, 32);   // partner unit (u_o ^ 1)
      if ((tid & 32) == 0) {                 // u_o even: pack (u, u+1)
        const half2v p = pack2h(h, hp2);
        __hip_atomic_store(&hGd[((size_t)t * BB + b_o) * 256 + blk * 2 + (u_o >> 1)],
                           __builtin_bit_cast(unsigned int, p),
                           __ATOMIC_RELAXED, __HIP_MEMORY_SCOPE_AGENT);
      }
    }
    __syncthreads();   // drains vmcnt => h stores acked at LLC
    if (tid == 0)
      __hip_atomic_store(&flgd[(s * NBLK + blk) * FSTR], 1, __ATOMIC_RELAXED,
                         __HIP_MEMORY_SCOPE_AGENT);
  }
}

// ---------------- dense + SELU (reads packed-f16 h) ----------------
__global__ __launch_bounds__(256) void dense_selu(
    const unsigned int* __restrict__ hGf, const unsigned int* __restrict__ hGb,
    const float* __restrict__ W, const float* __restrict__ bias,
    float* __restrict__ out)
{
  const int bt = blockIdx.x;
  const int b = bt >> 8, t = bt & 255;
  __shared__ float h[1024];
  __shared__ float part[8][33];
  const int tid = threadIdx.x;
  {
    const unsigned int wf = hGf[((size_t)t * BB + b) * 256 + tid];
    const unsigned int wb = hGb[((size_t)t * BB + b) * 256 + tid];
    const half2v f = __builtin_bit_cast(half2v, wf);
    const half2v g = __builtin_bit_cast(half2v, wb);
    h[2 * tid]       = (float)f.x;
    h[2 * tid + 1]   = (float)f.y;
    h[512 + 2 * tid]     = (float)g.x;
    h[512 + 2 * tid + 1] = (float)g.y;
  }
  __syncthreads();
  const int n = tid & 31, s8 = tid >> 5;   // s8: 8 k-slices of 128
  if (n < NTAG) {
    float acc = 0.f;
    const int k0 = s8 * 128;
    #pragma unroll 4
    for (int k = k0; k < k0 + 128; ++k) acc = fmaf(h[k], W[(size_t)k * NTAG + n], acc);
    part[s8][n] = acc;
  }
  __syncthreads();
  if (tid < NTAG) {
    float v = 0.f;
    #pragma unroll
    for (int q = 0; q < 8; ++q) v += part[q][tid];
    v += bias[tid];
    const float scale = 1.0507009873554805f, alf = 1.6732632423543772f;
    v = v > 0.f ? scale * v : scale * alf * (__expf(v) - 1.f);
    out[(size_t)bt * NTAG + tid] = v;
  }
}

// ---------------- CRF NLL ----------------
__global__ __launch_bounds__(64) void crf_kernel(
    const float* __restrict__ logits,
    const int* __restrict__ tags, const int* __restrict__ lens,
    const float* __restrict__ trans, float* __restrict__ nll)
{
  const int b = blockIdx.x;
  const int tid = threadIdx.x;
  __shared__ float tr[NTAG * NTAG];
  __shared__ float al[NTAG];
  __shared__ float red[2];
  for (int i = tid; i < NTAG * NTAG; i += 64) tr[i] = trans[i];
  __syncthreads();

  int len = lens[b];
  len = len < 1 ? 1 : (len > TT ? TT : len);
  const size_t base = (size_t)b * TT;

  float us = 0.f, bs = 0.f;
  for (int t = tid; t < TT; t += 64) {
    if (t < len) us += logits[(base + t) * NTAG + tags[base + t]];
    if (t >= 1 && t < len) bs += tr[tags[base + t - 1] * NTAG + tags[base + t]];
  }
  #pragma unroll
  for (int off = 32; off > 0; off >>= 1) {
    us += __shfl_down(us, off);
    bs += __shfl_down(bs, off);
  }
  if (tid == 0) { red[0] = us; red[1] = bs; }

  if (tid < NTAG) al[tid] = logits[base * NTAG + tid];
  __syncthreads();

  for (int t = 1; t < len; ++t) {
    float nv = 0.f;
    if (tid < NTAG) {
      float m = -3.4e38f;
      #pragma unroll
      for (int i = 0; i < NTAG; ++i) m = fmaxf(m, al[i] + tr[i * NTAG + tid]);
      float ss = 0.f;
      #pragma unroll
      for (int i = 0; i < NTAG; ++i) ss += __expf(al[i] + tr[i * NTAG + tid] - m);
      nv = m + __logf(ss) + logits[(base + t) * NTAG + tid];
    }
    __syncthreads();
    if (tid < NTAG) al[tid] = nv;
    __syncthreads();
  }

  if (tid == 0) {
    float m = -3.4e38f;
    for (int i = 0; i < NTAG; ++i) m = fmaxf(m, al[i]);
    float ss = 0.f;
    for (int i = 0; i < NTAG; ++i) ss += __expf(al[i] - m);
    const float logz = m + __logf(ss);
    nll[b] = -(red[0] + red[1] - logz);
  }
}

__global__ __launch_bounds__(64) void finalize(const float* __restrict__ nll, float* __restrict__ out) {
  float v = (threadIdx.x < BB) ? nll[threadIdx.x] : 0.f;
  #pragma unroll
  for (int off = 32; off > 0; off >>= 1) v += __shfl_down(v, off);
  if (threadIdx.x == 0) out[0] = v * (1.f / BB);
}

extern "C" void kernel_launch(void* const* d_in, const int* in_sizes, int n_in,
                              void* d_out, int out_size, void* d_ws, size_t ws_size,
                              hipStream_t stream) {
  const float* emb  = (const float*)d_in[0];
  const int* tags   = (const int*)d_in[1];
  const int* lens   = (const int*)d_in[2];
  const float* kf   = (const float*)d_in[3];
  const float* rf   = (const float*)d_in[4];
  const float* bf   = (const float*)d_in[5];
  const float* kb   = (const float*)d_in[6];
  const float* rb   = (const float*)d_in[7];
  const float* bb   = (const float*)d_in[8];
  const float* dw   = (const float*)d_in[9];
  const float* db   = (const float*)d_in[10];
  const float* trans= (const float*)d_in[11];
  float* out = (float*)d_out;

  float* ws  = (float*)d_ws;
  float* xzf = ws;
  float* xzb = xzf + (size_t)BT * GATES;
  unsigned int* hGf = (unsigned int*)(xzb + (size_t)BT * GATES);  // TT*BB*256 dwords = 8 MB
  unsigned int* hGb = hGf + (size_t)TT * BB * 256;
  unsigned short* KTf = (unsigned short*)(hGb + (size_t)TT * BB * 256);  // 2048*768 f16
  unsigned short* KTb = KTf + (size_t)GATES * DIN;
  float* nll = (float*)(KTb + (size_t)GATES * DIN);
  int*   flg = (int*)(nll + 64);               // 2*256*128*4 = 262144 ints
  int*   ep  = flg + 2 * TT * NBLK * FSTR;     // 2*256*8*16  = 65536 ints

  // zero the step flags + epochs (required every call; graph-safe)
  (void)hipMemsetAsync(flg, 0,
                       (size_t)(2 * TT * NBLK * FSTR + 2 * TT * EREP * ESTR) * 4,
                       stream);

  transpose_k<<<dim3(DIN / 64, GATES / 64, 2), 256, 0, stream>>>(kf, kb, KTf, KTb);
  gemm_xz<<<dim3(GATES / 128, BT / 128, 2), 256, 0, stream>>>(emb, KTf, KTb, bf, bb, xzf, xzb);
  lstm_persist<<<2 * NBLK, 256, 0, stream>>>(xzf, xzb, rf, rb, hGf, hGb, flg, ep);
  dense_selu<<<8192, 256, 0, stream>>>(hGf, hGb, dw, db, out + 1);
  crf_kernel<<<32, 64, 0, stream>>>(out + 1, tags, lens, trans, nll);
  finalize<<<1, 64, 0, stream>>>(nll, out);
}

// Round 11
// 973.046 us; speedup vs baseline: 10.6360x; 1.0093x over previous
//
#include <hip/hip_runtime.h>
#include <hip/hip_bf16.h>
#include <math.h>

#define HID 512
#define GATES 2048
#define BT 8192   // 32*256
#define TT 256
#define BB 32
#define DIN 768
#define NTAG 25
#define UPB 4     // hidden units per persistent block
#define NBLK 128  // blocks per direction
#define FSTR 4    // flag stride in ints (16 B)
#define EREP 8    // epoch flag replicas
#define ESTR 16   // epoch replica stride in ints (64 B)

typedef _Float16 half2v __attribute__((ext_vector_type(2)));
typedef _Float16 half8  __attribute__((ext_vector_type(8)));
typedef float    f32x4  __attribute__((ext_vector_type(4)));

__device__ __forceinline__ half2v pack2h(float a, float b) {
  return __builtin_bit_cast(half2v, __builtin_amdgcn_cvt_pkrtz(a, b));
}

__device__ __forceinline__ float sigf(float x) { return 1.f / (1.f + __expf(-x)); }

// async global->LDS, 16B per lane; dest must be wave-uniform base (+lane*16)
__device__ __forceinline__ void gld_lds16(const void* g, void* l) {
  __builtin_amdgcn_global_load_lds(
      (const __attribute__((address_space(1))) unsigned int*)g,
      (__attribute__((address_space(3))) unsigned int*)l, 16, 0, 0);
}

// ---------------- prep: emb16[m][k] = (f16)emb[m][k], chunk-XOR-swizzled ----
// chunk (16B = 8 f16) s within each 64-k block stored at s^(m&7).
__global__ __launch_bounds__(256) void convert_emb(
    const float* __restrict__ emb, unsigned short* __restrict__ emb16)
{
  const int m = blockIdx.x * 8 + (threadIdx.x >> 5);
  const int c0 = threadIdx.x & 31;
  #pragma unroll
  for (int p = 0; p < 3; ++p) {
    const int c = c0 + p * 32;              // chunk 0..95
    const int kb = c >> 3, s = c & 7;
    const float* src = emb + (size_t)m * DIN + c * 8;
    const float4 v0 = *(const float4*)src;
    const float4 v1 = *(const float4*)(src + 4);
    half8 hv;
    hv[0] = (_Float16)v0.x; hv[1] = (_Float16)v0.y;
    hv[2] = (_Float16)v0.z; hv[3] = (_Float16)v0.w;
    hv[4] = (_Float16)v1.x; hv[5] = (_Float16)v1.y;
    hv[6] = (_Float16)v1.z; hv[7] = (_Float16)v1.w;
    *(half8*)(emb16 + (size_t)m * DIN + kb * 64 + (s ^ (m & 7)) * 8) = hv;
  }
}

// ---------------- prep: KT[n][k] = (f16)K[k][n], chunk-XOR-swizzled ---------
__global__ __launch_bounds__(256) void transpose_k(
    const float* __restrict__ Kf, const float* __restrict__ Kb,
    unsigned short* __restrict__ KTf, unsigned short* __restrict__ KTb)
{
  const int dir = blockIdx.z;
  const float* __restrict__ K = dir ? Kb : Kf;
  unsigned short* __restrict__ KT = dir ? KTb : KTf;
  const int k0 = blockIdx.x * 64;
  const int n0 = blockIdx.y * 64;
  __shared__ float tile[64][65];
  const int tid = threadIdx.x;
  #pragma unroll
  for (int p = 0; p < 4; ++p) {
    const int idx = p * 256 + tid;
    const int kr = idx >> 4, c4 = (idx & 15) * 4;
    const float4 v = *(const float4*)(K + (size_t)(k0 + kr) * GATES + n0 + c4);
    tile[kr][c4 + 0] = v.x; tile[kr][c4 + 1] = v.y;
    tile[kr][c4 + 2] = v.z; tile[kr][c4 + 3] = v.w;
  }
  __syncthreads();
  #pragma unroll
  for (int p = 0; p < 2; ++p) {
    const int idx = p * 256 + tid;
    const int nr = idx >> 3, s = idx & 7;   // chunk s of this 64-k block
    half8 hv;
    #pragma unroll
    for (int x = 0; x < 8; ++x) hv[x] = (_Float16)tile[s * 8 + x][nr];
    *(half8*)(KT + (size_t)(n0 + nr) * DIN + k0 + (s ^ (nr & 7)) * 8) = hv;
  }
}

// ---------------- prep: WT16[n][k] = (f16)W[k][n], n padded to 32 -----------
__global__ __launch_bounds__(256) void prep_w(
    const float* __restrict__ W, unsigned short* __restrict__ WT16)
{
  for (int id = threadIdx.x; id < 32 * 1024; id += 256) {
    const int n = id >> 10, k = id & 1023;
    const float v = (n < NTAG) ? W[(size_t)k * NTAG + n] : 0.f;
    ((_Float16*)WT16)[id] = (_Float16)v;
  }
}

// ---------------- GEMM (f16 MFMA + global_load_lds): xz = emb @ K + bias ----
// 128x128 tile, BK=64, 4 waves. Sources are PRE-SWIZZLED in memory, staged
// linearly via global_load_lds (16B), so frag ds_read_b128 uses the XOR
// pattern against a linear LDS copy of the swizzled layout.
__global__ __launch_bounds__(256) void gemm_xz(
    const unsigned short* __restrict__ emb16,
    const unsigned short* __restrict__ KTf, const unsigned short* __restrict__ KTb,
    const float* __restrict__ bf, const float* __restrict__ bb,
    float* __restrict__ xzf, float* __restrict__ xzb)
{
  const int dir = blockIdx.z;
  const unsigned short* __restrict__ KT = dir ? KTb : KTf;
  const float* __restrict__ bias = dir ? bb : bf;
  float* __restrict__ C = dir ? xzb : xzf;
  const int n0 = blockIdx.x * 128;
  const int m0 = blockIdx.y * 128;

  __shared__ __align__(16) char A_lds[128 * 64 * 2];  // 16 KB f16 [m][k] swz
  __shared__ __align__(16) char B_lds[128 * 64 * 2];  // 16 KB f16 [n][k] swz

  const int tid = threadIdx.x;
  const int lane = tid & 63, wid = tid >> 6;
  const int wm = wid >> 1, wn = wid & 1;
  const int lm = lane & 15, lk = lane >> 4;

  f32x4 acc[4][4];
  #pragma unroll
  for (int i = 0; i < 4; ++i)
    #pragma unroll
    for (int j = 0; j < 4; ++j) acc[i][j] = (f32x4){0.f, 0.f, 0.f, 0.f};

  for (int kt = 0; kt < DIN / 64; ++kt) {
    __syncthreads();    // previous iteration's frag reads complete
    #pragma unroll
    for (int i = 0; i < 4; ++i) {
      const int g = wid * 256 + i * 64 + lane;   // chunk 0..1023
      const int r = g >> 3, s = g & 7;
      gld_lds16(emb16 + (size_t)(m0 + r) * DIN + (kt * 8 + s) * 8,
                A_lds + (size_t)(wid * 256 + i * 64) * 16);
      gld_lds16(KT + (size_t)(n0 + r) * DIN + (kt * 8 + s) * 8,
                B_lds + (size_t)(wid * 256 + i * 64) * 16);
    }
    __syncthreads();    // barrier drains vmcnt -> LDS tiles ready

    #pragma unroll
    for (int kh = 0; kh < 2; ++kh) {
      half8 a[4], b[4];
      #pragma unroll
      for (int mt = 0; mt < 4; ++mt) {
        const int rloc = wm * 64 + mt * 16 + lm;
        const int kslot = kh * 4 + lk;
        a[mt] = *(const half8*)(A_lds + rloc * 128 + ((kslot ^ (rloc & 7)) << 4));
      }
      #pragma unroll
      for (int nt = 0; nt < 4; ++nt) {
        const int nloc = wn * 64 + nt * 16 + lm;
        const int kslot = kh * 4 + lk;
        b[nt] = *(const half8*)(B_lds + nloc * 128 + ((kslot ^ (nloc & 7)) << 4));
      }
      #pragma unroll
      for (int mt = 0; mt < 4; ++mt)
        #pragma unroll
        for (int nt = 0; nt < 4; ++nt)
          acc[mt][nt] = __builtin_amdgcn_mfma_f32_16x16x32_f16(a[mt], b[nt], acc[mt][nt], 0, 0, 0);
    }
  }

  #pragma unroll
  for (int nt = 0; nt < 4; ++nt) {
    const int col = n0 + wn * 64 + nt * 16 + lm;
    const float bs = bias[col];
    #pragma unroll
    for (int mt = 0; mt < 4; ++mt) {
      const int rowb = m0 + wm * 64 + mt * 16 + lk * 4;
      const f32x4 v = acc[mt][nt];
      #pragma unroll
      for (int g = 0; g < 4; ++g)
        C[(size_t)(rowb + g) * GATES + col] = v[g] + bs;
    }
  }
}

// ---------------- Persistent BiLSTM (fence-free, MFMA z-loop) ----------
// (unchanged from R10: 698 us, 2.73 us/step ~ sync-chain floor)
__global__ __launch_bounds__(256, 1) void lstm_persist(
    const float* __restrict__ xzf, const float* __restrict__ xzb,
    const float* __restrict__ Rf, const float* __restrict__ Rb,
    unsigned int* __restrict__ hGf, unsigned int* __restrict__ hGb,
    int* __restrict__ flg,    // [2 dir][256 step][NBLK * FSTR]
    int* __restrict__ ep)     // [2 dir][256 step][EREP * ESTR]
{
  const int bid = blockIdx.x;
  const int dir = bid & 1;
  const int blk = bid >> 1;            // 0..127
  const int u0 = blk * UPB;
  const int tid = threadIdx.x;
  const int c = tid & 15;
  const int j = (c & 3) * HID + u0 + (c >> 2);   // gate-major column
  const int lane = tid & 63, w = tid >> 6;
  const int lm = lane & 15, lk = lane >> 4;

  const float* __restrict__ R  = dir ? Rb : Rf;
  const float* __restrict__ xz = dir ? xzb : xzf;
  unsigned int* __restrict__ hGd = dir ? hGb : hGf;
  int* __restrict__ flgd = flg + (size_t)dir * TT * NBLK * FSTR;
  int* __restrict__ epd  = ep  + (size_t)dir * TT * EREP * ESTR;

  __shared__ uint4 hs4[BB * 65];
  __shared__ float redm[4][BB][18];
  __shared__ float zbuf[BB][20];

  half8 Rbf[4];
  #pragma unroll
  for (int kti = 0; kti < 4; ++kti) {
    const int kb = (w * 4 + kti) * 32 + lk * 8;
    half8 hv;
    #pragma unroll
    for (int x = 0; x < 8; ++x) hv[x] = (_Float16)R[(size_t)(kb + x) * GATES + j];
    Rbf[kti] = hv;
  }

  float cst = 0.f;
  const int b_o = tid & 31, u_o = tid >> 5;
  const int fb0 = tid >> 4, fb1 = (tid >> 4) + 16;
  const bool leader = (blk == 0);

  for (int s = 0; s < TT; ++s) {
    const int t = dir ? (TT - 1 - s) : s;

    const float x0 = xz[((size_t)fb0 * TT + t) * GATES + j];
    const float x1 = xz[((size_t)fb1 * TT + t) * GATES + j];

    if (s > 0) {
      const int tprev = dir ? t + 1 : t - 1;
      if (leader) {
        if (tid < NBLK) {
          while (!__hip_atomic_load(&flgd[((s - 1) * NBLK + tid) * FSTR],
                                    __ATOMIC_RELAXED, __HIP_MEMORY_SCOPE_AGENT))
            __builtin_amdgcn_s_sleep(1);
        }
        __syncthreads();
        if (tid < EREP)
          __hip_atomic_store(&epd[((s - 1) * EREP + tid) * ESTR], 1,
                             __ATOMIC_RELAXED, __HIP_MEMORY_SCOPE_AGENT);
      } else {
        if (tid == 0) {
          while (!__hip_atomic_load(&epd[((s - 1) * EREP + (blk & 7)) * ESTR],
                                    __ATOMIC_RELAXED, __HIP_MEMORY_SCOPE_AGENT))
            __builtin_amdgcn_s_sleep(1);
        }
        __syncthreads();
      }
      const uint4* hsrc = (const uint4*)(hGd + (size_t)tprev * BB * 256);
      #pragma unroll
      for (int it = 0; it < 8; ++it) {
        const int g4 = tid + it * 256;
        const uint4 v = hsrc[g4];
        hs4[(g4 >> 6) * 65 + (g4 & 63)] = v;
      }
    } else {
      const uint4 zz = make_uint4(0u, 0u, 0u, 0u);
      #pragma unroll
      for (int it = 0; it < 9; ++it) {
        const int idx = tid + it * 256;
        if (idx < BB * 65) hs4[idx] = zz;
      }
    }
    __syncthreads();

    f32x4 acc0 = (f32x4){0.f, 0.f, 0.f, 0.f};
    f32x4 acc1 = (f32x4){0.f, 0.f, 0.f, 0.f};
    #pragma unroll
    for (int kti = 0; kti < 4; ++kti) {
      const int k4 = (w * 4 + kti) * 4 + lk;
      const half8 a0 = *(const half8*)&hs4[(lm) * 65 + k4];
      const half8 a1 = *(const half8*)&hs4[(16 + lm) * 65 + k4];
      acc0 = __builtin_amdgcn_mfma_f32_16x16x32_f16(a0, Rbf[kti], acc0, 0, 0, 0);
      acc1 = __builtin_amdgcn_mfma_f32_16x16x32_f16(a1, Rbf[kti], acc1, 0, 0, 0);
    }
    #pragma unroll
    for (int g = 0; g < 4; ++g) {
      redm[w][lk * 4 + g][lm] = acc0[g];
      redm[w][16 + lk * 4 + g][lm] = acc1[g];
    }
    __syncthreads();

    {
      const float za = redm[0][fb0][c] + redm[1][fb0][c] + redm[2][fb0][c] + redm[3][fb0][c] + x0;
      const float zb2 = redm[0][fb1][c] + redm[1][fb1][c] + redm[2][fb1][c] + redm[3][fb1][c] + x1;
      zbuf[fb0][c] = za;
      zbuf[fb1][c] = zb2;
    }
    __syncthreads();

    if (tid < 128) {
      const float zi = zbuf[b_o][u_o * 4 + 0];
      const float zf = zbuf[b_o][u_o * 4 + 1];
      const float zg = zbuf[b_o][u_o * 4 + 2];
      const float zo = zbuf[b_o][u_o * 4 + 3];
      cst = sigf(zf) * cst + sigf(zi) * tanhf(zg);
      const float h = sigf(zo) * tanhf(cst);
      const float hp2 = __shfl_xor(h, 32);
      if ((tid & 32) == 0) {
        const half2v p = pack2h(h, hp2);
        __hip_atomic_store(&hGd[((size_t)t * BB + b_o) * 256 + blk * 2 + (u_o >> 1)],
                           __builtin_bit_cast(unsigned int, p),
                           __ATOMIC_RELAXED, __HIP_MEMORY_SCOPE_AGENT);
      }
    }
    __syncthreads();
    if (tid == 0)
      __hip_atomic_store(&flgd[(s * NBLK + blk) * FSTR], 1, __ATOMIC_RELAXED,
                         __HIP_MEMORY_SCOPE_AGENT);
  }
}

// ---------------- dense + SELU as MFMA GEMM: [8192x1024]@[1024x32] ----------
// Row q = t*32+b (hG-contiguous); 64 blocks x 128 rows; SELU fused epilogue.
__global__ __launch_bounds__(256) void dense_selu(
    const unsigned int* __restrict__ hGf, const unsigned int* __restrict__ hGb,
    const unsigned short* __restrict__ WT16, const float* __restrict__ bias,
    float* __restrict__ out)
{
  const int q0 = blockIdx.x * 128;
  __shared__ __align__(16) char A_lds[128 * 64 * 2];  // 16 KB
  __shared__ __align__(16) char B_lds[32 * 64 * 2];   // 4 KB

  const int tid = threadIdx.x;
  const int lane = tid & 63, w = tid >> 6;
  const int lm = lane & 15, lk = lane >> 4;

  f32x4 acc[2][2];
  #pragma unroll
  for (int i = 0; i < 2; ++i)
    #pragma unroll
    for (int jj = 0; jj < 2; ++jj) acc[i][jj] = (f32x4){0.f, 0.f, 0.f, 0.f};

  for (int kt = 0; kt < 16; ++kt) {
    const int k0 = kt * 64;
    __syncthreads();
    // stage A: 128 rows x 8 chunks (reg-staged, XOR-swizzled writes)
    #pragma unroll
    for (int p = 0; p < 4; ++p) {
      const int id = p * 256 + tid;
      const int r = id >> 3, s = id & 7;
      const int k = k0 + s * 8;
      const unsigned int* src = (k < 512)
          ? hGf + (size_t)(q0 + r) * 256 + (k >> 1)
          : hGb + (size_t)(q0 + r) * 256 + ((k - 512) >> 1);
      const uint4 v = *(const uint4*)src;
      *(uint4*)(A_lds + r * 128 + ((s ^ (r & 7)) << 4)) = v;
    }
    // stage B: 32 rows x 8 chunks
    {
      const int r = tid >> 3, s = tid & 7;
      const uint4 v = *(const uint4*)(WT16 + (size_t)r * 1024 + k0 + s * 8);
      *(uint4*)(B_lds + r * 128 + ((s ^ (r & 7)) << 4)) = v;
    }
    __syncthreads();

    #pragma unroll
    for (int kh = 0; kh < 2; ++kh) {
      const int kslot = kh * 4 + lk;
      half8 a[2], b[2];
      #pragma unroll
      for (int mt = 0; mt < 2; ++mt) {
        const int rloc = w * 32 + mt * 16 + lm;
        a[mt] = *(const half8*)(A_lds + rloc * 128 + ((kslot ^ (rloc & 7)) << 4));
      }
      #pragma unroll
      for (int nt = 0; nt < 2; ++nt) {
        const int nloc = nt * 16 + lm;
        b[nt] = *(const half8*)(B_lds + nloc * 128 + ((kslot ^ (nloc & 7)) << 4));
      }
      #pragma unroll
      for (int mt = 0; mt < 2; ++mt)
        #pragma unroll
        for (int nt = 0; nt < 2; ++nt)
          acc[mt][nt] = __builtin_amdgcn_mfma_f32_16x16x32_f16(a[mt], b[nt], acc[mt][nt], 0, 0, 0);
    }
  }

  const float scale = 1.0507009873554805f, alf = 1.6732632423543772f;
  #pragma unroll
  for (int nt = 0; nt < 2; ++nt) {
    const int col = nt * 16 + lm;
    if (col < NTAG) {
      const float bs = bias[col];
      #pragma unroll
      for (int mt = 0; mt < 2; ++mt) {
        const int rowb = q0 + w * 32 + mt * 16 + lk * 4;
        const f32x4 vv = acc[mt][nt];
        #pragma unroll
        for (int g = 0; g < 4; ++g) {
          const int q = rowb + g;
          const int bt = (q & 31) * 256 + (q >> 5);
          float v = vv[g] + bs;
          v = v > 0.f ? scale * v : scale * alf * (__expf(v) - 1.f);
          out[(size_t)bt * NTAG + col] = v;
        }
      }
    }
  }
}

// ---------------- CRF NLL ----------------
__global__ __launch_bounds__(64) void crf_kernel(
    const float* __restrict__ logits,
    const int* __restrict__ tags, const int* __restrict__ lens,
    const float* __restrict__ trans, float* __restrict__ nll)
{
  const int b = blockIdx.x;
  const int tid = threadIdx.x;
  __shared__ float tr[NTAG * NTAG];
  __shared__ float al[NTAG];
  __shared__ float red[2];
  for (int i = tid; i < NTAG * NTAG; i += 64) tr[i] = trans[i];
  __syncthreads();

  int len = lens[b];
  len = len < 1 ? 1 : (len > TT ? TT : len);
  const size_t base = (size_t)b * TT;

  float us = 0.f, bs = 0.f;
  for (int t = tid; t < TT; t += 64) {
    if (t < len) us += logits[(base + t) * NTAG + tags[base + t]];
    if (t >= 1 && t < len) bs += tr[tags[base + t - 1] * NTAG + tags[base + t]];
  }
  #pragma unroll
  for (int off = 32; off > 0; off >>= 1) {
    us += __shfl_down(us, off);
    bs += __shfl_down(bs, off);
  }
  if (tid == 0) { red[0] = us; red[1] = bs; }

  if (tid < NTAG) al[tid] = logits[base * NTAG + tid];
  __syncthreads();

  for (int t = 1; t < len; ++t) {
    float nv = 0.f;
    if (tid < NTAG) {
      float m = -3.4e38f;
      #pragma unroll
      for (int i = 0; i < NTAG; ++i) m = fmaxf(m, al[i] + tr[i * NTAG + tid]);
      float ss = 0.f;
      #pragma unroll
      for (int i = 0; i < NTAG; ++i) ss += __expf(al[i] + tr[i * NTAG + tid] - m);
      nv = m + __logf(ss) + logits[(base + t) * NTAG + tid];
    }
    __syncthreads();
    if (tid < NTAG) al[tid] = nv;
    __syncthreads();
  }

  if (tid == 0) {
    float m = -3.4e38f;
    for (int i = 0; i < NTAG; ++i) m = fmaxf(m, al[i]);
    float ss = 0.f;
    for (int i = 0; i < NTAG; ++i) ss += __expf(al[i] - m);
    const float logz = m + __logf(ss);
    nll[b] = -(red[0] + red[1] - logz);
  }
}

__global__ __launch_bounds__(64) void finalize(const float* __restrict__ nll, float* __restrict__ out) {
  float v = (threadIdx.x < BB) ? nll[threadIdx.x] : 0.f;
  #pragma unroll
  for (int off = 32; off > 0; off >>= 1) v += __shfl_down(v, off);
  if (threadIdx.x == 0) out[0] = v * (1.f / BB);
}

extern "C" void kernel_launch(void* const* d_in, const int* in_sizes, int n_in,
                              void* d_out, int out_size, void* d_ws, size_t ws_size,
                              hipStream_t stream) {
  const float* emb  = (const float*)d_in[0];
  const int* tags   = (const int*)d_in[1];
  const int* lens   = (const int*)d_in[2];
  const float* kf   = (const float*)d_in[3];
  const float* rf   = (const float*)d_in[4];
  const float* bf   = (const float*)d_in[5];
  const float* kb   = (const float*)d_in[6];
  const float* rb   = (const float*)d_in[7];
  const float* bb   = (const float*)d_in[8];
  const float* dw   = (const float*)d_in[9];
  const float* db   = (const float*)d_in[10];
  const float* trans= (const float*)d_in[11];
  float* out = (float*)d_out;

  float* ws  = (float*)d_ws;
  float* xzf = ws;
  float* xzb = xzf + (size_t)BT * GATES;
  unsigned int* hGf = (unsigned int*)(xzb + (size_t)BT * GATES);  // 8 MB
  unsigned int* hGb = hGf + (size_t)TT * BB * 256;
  unsigned short* emb16 = (unsigned short*)(hGb + (size_t)TT * BB * 256); // 12.6 MB
  unsigned short* KTf = emb16 + (size_t)BT * DIN;                 // 3.1 MB each
  unsigned short* KTb = KTf + (size_t)GATES * DIN;
  unsigned short* WT16 = KTb + (size_t)GATES * DIN;               // 64 KB
  float* nll = (float*)(WT16 + 32 * 1024);
  int*   flg = (int*)(nll + 64);
  int*   ep  = flg + 2 * TT * NBLK * FSTR;

  (void)hipMemsetAsync(flg, 0,
                       (size_t)(2 * TT * NBLK * FSTR + 2 * TT * EREP * ESTR) * 4,
                       stream);

  convert_emb<<<BT / 8, 256, 0, stream>>>(emb, emb16);
  transpose_k<<<dim3(DIN / 64, GATES / 64, 2), 256, 0, stream>>>(kf, kb, KTf, KTb);
  prep_w<<<1, 256, 0, stream>>>(dw, WT16);
  gemm_xz<<<dim3(GATES / 128, BT / 128, 2), 256, 0, stream>>>(emb16, KTf, KTb, bf, bb, xzf, xzb);
  lstm_persist<<<2 * NBLK, 256, 0, stream>>>(xzf, xzb, rf, rb, hGf, hGb, flg, ep);
  dense_selu<<<BT / 128, 256, 0, stream>>>(hGf, hGb, WT16, db, out + 1);
  crf_kernel<<<32, 64, 0, stream>>>(out + 1, tags, lens, trans, nll);
  finalize<<<1, 64, 0, stream>>>(nll, out);
}